// Round 3
// baseline (820.200 us; speedup 1.0000x reference)
//
#include <hip/hip_runtime.h>

typedef unsigned short u16;

__device__ inline float b2f(u16 u) {
    union { unsigned int i; float f; } c; c.i = ((unsigned int)u) << 16; return c.f;
}
__device__ inline u16 f2b(float f) {
    union { float f; unsigned int i; } c; c.f = f;
    unsigned int i = c.i;
    i += 0x7fffu + ((i >> 16) & 1u);   // RTNE
    return (u16)(i >> 16);
}

// generic intermediate storage (fp32, or bf16 if workspace is tight)
template <typename T> __device__ inline float ldH(const T* p, size_t i);
template <> __device__ inline float ldH<float>(const float* p, size_t i) { return p[i]; }
template <> __device__ inline float ldH<u16>(const u16* p, size_t i) { return b2f(p[i]); }
template <typename T> __device__ inline void stH(T* p, size_t i, float v);
template <> __device__ inline void stH<float>(float* p, size_t i, float v) { p[i] = v; }
template <> __device__ inline void stH<u16>(u16* p, size_t i, float v) { p[i] = f2b(v); }

// ---------------- weight pre-transpose (fp32):  Wt[n][k] ----------------
// W1t[n=h*64+f][k] = W_heads[h][k][f]   (256 x 128)
__global__ void prep_w1t(const float* __restrict__ Wh, float* __restrict__ W1t) {
    int i = blockIdx.x * 256 + threadIdx.x;
    if (i >= 256 * 128) return;
    int n = i >> 7, k = i & 127;
    int h = n >> 6, f = n & 63;
    W1t[i] = Wh[h * (128 * 64) + k * 64 + f];
}
// W2t[n][k] = W_out[k][n]   (64 x 256)
__global__ void prep_w2t(const float* __restrict__ Wo, float* __restrict__ W2t) {
    int i = blockIdx.x * 256 + threadIdx.x;
    if (i >= 64 * 256) return;
    int n = i >> 8, k = i & 255;
    W2t[i] = Wo[k * 64 + n];
}

// ---------------- zero helper ----------------
__global__ void zero2(int* __restrict__ a, int* __restrict__ b, int n) {
    int i = blockIdx.x * 256 + threadIdx.x;
    if (i < n) { a[i] = 0; b[i] = 0; }
}

// ---------------- CSR build (edge_index is int32) ----------------
__global__ void count_edges(const int* __restrict__ src, int* __restrict__ counts, int E, int N) {
    int e = blockIdx.x * 256 + threadIdx.x;
    if (e >= E) return;
    int s = src[e];
    s = ((unsigned)s < (unsigned)N) ? s : 0;
    atomicAdd(&counts[s], 1);
}

__global__ void scan_kernel(const int* __restrict__ counts, int* __restrict__ row_start, int n) {
    const int t = threadIdx.x, lane = t & 63, w = t >> 6;   // 16 waves
    __shared__ int wsum[16];
    __shared__ int carry;
    if (t == 0) carry = 0;
    __syncthreads();
    for (int base = 0; base < n; base += 1024) {
        int i = base + t;
        int v = (i < n) ? counts[i] : 0;
        int orig = v;
        for (int d = 1; d < 64; d <<= 1) { int x = __shfl_up(v, d); if (lane >= d) v += x; }
        if (lane == 63) wsum[w] = v;
        __syncthreads();
        if (t == 0) {
            int acc = carry;
            for (int j = 0; j < 16; j++) { int tmp = wsum[j]; wsum[j] = acc; acc += tmp; }
            carry = acc;
        }
        __syncthreads();
        if (i < n) row_start[i] = wsum[w] + (v - orig);   // exclusive prefix
        __syncthreads();
    }
    if (t == 0) row_start[n] = carry;
}

__global__ void scatter_edges(const int* __restrict__ src, const int* __restrict__ dst,
                              const int* __restrict__ row_start, int* __restrict__ cursor,
                              int* __restrict__ edge_dst, int E, int N) {
    int e = blockIdx.x * 256 + threadIdx.x;
    if (e >= E) return;
    int s = src[e];
    s = ((unsigned)s < (unsigned)N) ? s : 0;
    int d = dst[e];
    d = ((unsigned)d < (unsigned)N) ? d : 0;
    int pos = atomicAdd(&cursor[s], 1);
    int idx = row_start[s] + pos;
    if ((unsigned)idx < (unsigned)E) edge_dst[idx] = d;
}

// ---------------- GEMM1 (fp32 VALU): C[M x 256] = X[M x 128] @ W1t^T ----------------
// one block: 16 rows, 256 threads = 256 output cols; X tile staged in LDS
template <typename OT>
__global__ __launch_bounds__(256) void gemm1(const float* __restrict__ X, const float* __restrict__ W1t,
                                             OT* __restrict__ C, int M) {
    __shared__ float Xs[16 * 128];
    const int m0 = blockIdx.x * 16;
    const int t = threadIdx.x;
    float4* Xs4 = (float4*)Xs;
    if (m0 + 16 <= M) {
        const float4* s4 = (const float4*)(X + (size_t)m0 * 128);
        for (int i = t; i < 512; i += 256) Xs4[i] = s4[i];
    } else {
        for (int i = t; i < 2048; i += 256) {
            int r = i >> 7;
            Xs[i] = (m0 + r < M) ? X[(size_t)(m0 + r) * 128 + (i & 127)] : 0.f;
        }
    }
    __syncthreads();
    float acc[16];
#pragma unroll
    for (int r = 0; r < 16; r++) acc[r] = 0.f;
    const float4* w4p = (const float4*)(W1t + t * 128);
    for (int kq = 0; kq < 32; kq++) {
        float4 w = w4p[kq];
#pragma unroll
        for (int r = 0; r < 16; r++) {
            float4 xv = Xs4[r * 32 + kq];
            acc[r] += xv.x * w.x + xv.y * w.y + xv.z * w.z + xv.w * w.w;
        }
    }
#pragma unroll
    for (int r = 0; r < 16; r++)
        if (m0 + r < M) stH(C, (size_t)(m0 + r) * 256 + t, acc[r]);
}

// ---------------- GEMM2 (fp32 VALU): C[M x 64] = Hc[M x 256] @ W2t^T ----------------
// one block: 16 rows; thread = (col n = t&63, row-quad rq = t>>6)
template <typename IT, typename OT>
__global__ __launch_bounds__(256) void gemm2(const IT* __restrict__ Hc, const float* __restrict__ W2t,
                                             OT* __restrict__ C, int M) {
    __shared__ float Xs[16 * 256];
    const int m0 = blockIdx.x * 16;
    const int t = threadIdx.x;
    for (int i = t; i < 4096; i += 256) {
        int r = i >> 8;
        Xs[i] = (m0 + r < M) ? ldH(Hc, (size_t)(m0 + r) * 256 + (i & 255)) : 0.f;
    }
    __syncthreads();
    const int n = t & 63, rq = t >> 6;
    float acc[4] = {0.f, 0.f, 0.f, 0.f};
    const float4* w4p = (const float4*)(W2t + n * 256);
    const float4* Xs4 = (const float4*)Xs;
    for (int kq = 0; kq < 64; kq++) {
        float4 w = w4p[kq];
#pragma unroll
        for (int i = 0; i < 4; i++) {
            float4 xv = Xs4[(rq * 4 + i) * 64 + kq];
            acc[i] += xv.x * w.x + xv.y * w.y + xv.z * w.z + xv.w * w.w;
        }
    }
#pragma unroll
    for (int i = 0; i < 4; i++) {
        int r = rq * 4 + i;
        if (m0 + r < M) stH(C, (size_t)(m0 + r) * 64 + n, acc[i]);
    }
}

// ---------------- per-node attention scalars ----------------
template <int NH, int NPB, typename HT>
__global__ void compute_s(const HT* __restrict__ H, const float* __restrict__ attn,
                          float* __restrict__ s1, float* __restrict__ s2, int N) {
    const int t = threadIdx.x, lane = t & 63, wave = t >> 6;
    const int node = blockIdx.x * NPB + wave / NH;
    const int h = wave % NH;
    if (node >= N) return;
    float v = ldH(H, (size_t)node * (64 * NH) + h * 64 + lane);
    float p1 = v * attn[h * 128 + lane];
    float p2 = v * attn[h * 128 + 64 + lane];
    for (int d = 32; d > 0; d >>= 1) { p1 += __shfl_down(p1, d); p2 += __shfl_down(p2, d); }
    if (lane == 0) { s1[node * NH + h] = p1; s2[node * NH + h] = p2; }
}

// ---------------- fused per-node softmax + aggregation (one wave per node*head) ----------------
template <int NH, int NPB, bool ELU, typename HT, typename OT>
__global__ void aggregate(const int* __restrict__ row_start, const int* __restrict__ edge_dst,
                          const float* __restrict__ s1, const float* __restrict__ s2,
                          const HT* __restrict__ H, OT* __restrict__ out, int N, int E) {
    constexpr int FD = 64 * NH;
    const int t = threadIdx.x, lane = t & 63, wave = t >> 6;
    const int node = blockIdx.x * NPB + wave / NH;
    const int h = wave % NH;
    if (node >= N) return;
    int beg = row_start[node], end = row_start[node + 1];
    beg = (beg < 0) ? 0 : ((beg > E) ? E : beg);
    end = (end < beg) ? beg : ((end > E) ? E : end);
    if (beg == end) { stH(out, (size_t)node * FD + h * 64 + lane, 0.f); return; }
    const float s1v = s1[node * NH + h];

    // phase A: online softmax (max + denom)
    float m = -1e30f, sum = 0.f;
    for (int e = beg + lane; e < end; e += 64) {
        int d = edge_dst[e];
        d = ((unsigned)d < (unsigned)N) ? d : 0;
        float z = s1v + s2[d * NH + h];
        float sc = (z > 0.f) ? -z : -0.01f * z;    // -leaky_relu
        sc = fminf(fmaxf(sc, -1e4f), 1e4f);
        if (sc > m) { sum = sum * __expf(m - sc) + 1.f; m = sc; }
        else        { sum += __expf(sc - m); }
    }
    for (int off = 32; off > 0; off >>= 1) {
        float m2 = __shfl_xor(m, off);
        float sm2 = __shfl_xor(sum, off);
        float mn = fmaxf(m, m2);
        sum = sum * __expf(m - mn) + sm2 * __expf(m2 - mn);
        m = mn;
    }
    const float inv = (sum > 0.f) ? 1.f / sum : 0.f;

    // phase B: weighted feature aggregation (lane = feature)
    float acc = 0.f;
    for (int e = beg; e < end; e++) {
        int d = edge_dst[e];
        d = ((unsigned)d < (unsigned)N) ? d : 0;
        float z = s1v + s2[d * NH + h];
        float sc = (z > 0.f) ? -z : -0.01f * z;
        sc = fminf(fmaxf(sc, -1e4f), 1e4f);
        float wgt = __expf(sc - m) * inv;
        acc += wgt * ldH(H, (size_t)d * FD + h * 64 + lane);
    }
    float val = acc;
    if (ELU) val = (val > 0.f) ? val : (__expf(val) - 1.f);
    stH(out, (size_t)node * FD + h * 64 + lane, val);
}

// ---------------- host pipeline, templated on intermediate storage ----------------
template <typename HT1, typename HTC, typename HT2>
static void run_pipeline(const float* x, const int* srcp, const int* dstp,
                         const float* Wh, const float* attnH, const float* Wo, const float* attnO,
                         float* out, char* base, int N, int E, hipStream_t stream) {
    size_t off = 0;
    auto take = [&](size_t b) { void* p = base + off; off += (b + 255) & ~(size_t)255; return p; };
    float* W1t    = (float*)take(256 * 128 * 4);
    float* W2t    = (float*)take(64 * 256 * 4);
    int*   counts = (int*)  take((size_t)N * 4);
    int*   cursor = (int*)  take((size_t)N * 4);
    int*   rowst  = (int*)  take((size_t)(N + 1) * 4);
    int*   edged  = (int*)  take((size_t)E * 4);
    float* s1     = (float*)take((size_t)N * 4 * 4);
    float* s2     = (float*)take((size_t)N * 4 * 4);
    float* s1b    = (float*)take((size_t)N * 4);
    float* s2b    = (float*)take((size_t)N * 4);
    HT1*   H1     = (HT1*)  take((size_t)N * 256 * sizeof(HT1));
    HTC*   hcat   = (HTC*)  take((size_t)N * 256 * sizeof(HTC));
    HT2*   H2     = (HT2*)  take((size_t)N * 64 * sizeof(HT2));

    prep_w1t<<<128, 256, 0, stream>>>(Wh, W1t);
    prep_w2t<<<64, 256, 0, stream>>>(Wo, W2t);
    zero2<<<(N + 255) / 256, 256, 0, stream>>>(counts, cursor, N);

    count_edges<<<(E + 255) / 256, 256, 0, stream>>>(srcp, counts, E, N);
    scan_kernel<<<1, 1024, 0, stream>>>(counts, rowst, N);
    scatter_edges<<<(E + 255) / 256, 256, 0, stream>>>(srcp, dstp, rowst, cursor, edged, E, N);

    const int rowBlocks = (N + 15) / 16;
    gemm1<<<rowBlocks, 256, 0, stream>>>(x, W1t, H1, N);
    compute_s<4, 1><<<N, 256, 0, stream>>>(H1, attnH, s1, s2, N);
    aggregate<4, 1, true><<<N, 256, 0, stream>>>(rowst, edged, s1, s2, H1, hcat, N, E);

    gemm2<<<rowBlocks, 256, 0, stream>>>(hcat, W2t, H2, N);
    compute_s<1, 4><<<(N + 3) / 4, 256, 0, stream>>>(H2, attnO, s1b, s2b, N);
    aggregate<1, 4, false><<<(N + 3) / 4, 256, 0, stream>>>(rowst, edged, s1b, s2b, H2, out, N, E);
}

extern "C" void kernel_launch(void* const* d_in, const int* in_sizes, int n_in,
                              void* d_out, int out_size, void* d_ws, size_t ws_size,
                              hipStream_t stream) {
    const float* x     = (const float*)d_in[0];
    const int*   ei    = (const int*)d_in[1];     // [2][E] int32
    const float* Wh    = (const float*)d_in[2];
    const float* attnH = (const float*)d_in[3];
    const float* Wo    = (const float*)d_in[4];
    const float* attnO = (const float*)d_in[5];
    float* out         = (float*)d_out;

    const int N = in_sizes[0] / 128;    // 50000
    const int E = in_sizes[1] / 2;      // 800000
    const int* srcp = ei;
    const int* dstp = ei + E;

    // misc footprint (aligned): W1t+W2t+counts+cursor+rowst+edged+s1+s2+s1b+s2b
    auto al = [](size_t b) { return (b + 255) & ~(size_t)255; };
    size_t misc = al(256 * 128 * 4) + al(64 * 256 * 4) + 2 * al((size_t)N * 4) +
                  al((size_t)(N + 1) * 4) + al((size_t)E * 4) +
                  2 * al((size_t)N * 16) + 2 * al((size_t)N * 4);
    size_t h256f = al((size_t)N * 256 * 4), h256b = al((size_t)N * 256 * 2);
    size_t h64f = al((size_t)N * 64 * 4), h64b = al((size_t)N * 64 * 2);

    char* ws = (char*)d_ws;
    if (ws_size >= misc + 2 * h256f + h64f)          // plan A: all fp32 (~121 MB)
        run_pipeline<float, float, float>(x, srcp, dstp, Wh, attnH, Wo, attnO, out, ws, N, E, stream);
    else if (ws_size >= misc + h256f + h256b + h64f) // plan B: hcat bf16 (~96 MB)
        run_pipeline<float, u16, float>(x, srcp, dstp, Wh, attnH, Wo, attnO, out, ws, N, E, stream);
    else if (ws_size >= misc + 2 * h256b + h64f)     // plan C: H1+hcat bf16 (~70 MB)
        run_pipeline<u16, u16, float>(x, srcp, dstp, Wh, attnH, Wo, attnO, out, ws, N, E, stream);
    else                                             // plan D: all bf16 (~64 MB)
        run_pipeline<u16, u16, u16>(x, srcp, dstp, Wh, attnH, Wo, attnO, out, ws, N, E, stream);
}

// Round 4
// 555.731 us; speedup vs baseline: 1.4759x; 1.4759x over previous
//
#include <hip/hip_runtime.h>

typedef unsigned short u16;

__device__ inline float b2f(u16 u) {
    union { unsigned int i; float f; } c; c.i = ((unsigned int)u) << 16; return c.f;
}
__device__ inline u16 f2b(float f) {
    union { float f; unsigned int i; } c; c.f = f;
    unsigned int i = c.i;
    i += 0x7fffu + ((i >> 16) & 1u);   // RTNE
    return (u16)(i >> 16);
}

// scalar generic storage
template <typename T> __device__ inline float ldH(const T* p, size_t i);
template <> __device__ inline float ldH<float>(const float* p, size_t i) { return p[i]; }
template <> __device__ inline float ldH<u16>(const u16* p, size_t i) { return b2f(p[i]); }
template <typename T> __device__ inline void stH(T* p, size_t i, float v);
template <> __device__ inline void stH<float>(float* p, size_t i, float v) { p[i] = v; }
template <> __device__ inline void stH<u16>(u16* p, size_t i, float v) { p[i] = f2b(v); }

// vector4 generic storage
template <typename T> __device__ inline float4 ld4(const T* p, size_t i);
template <> __device__ inline float4 ld4<float>(const float* p, size_t i) { return *(const float4*)(p + i); }
template <> __device__ inline float4 ld4<u16>(const u16* p, size_t i) {
    ushort4 u = *(const ushort4*)(p + i);
    return make_float4(b2f(u.x), b2f(u.y), b2f(u.z), b2f(u.w));
}
template <typename T> __device__ inline void st4(T* p, size_t i, float4 v);
template <> __device__ inline void st4<float>(float* p, size_t i, float4 v) { *(float4*)(p + i) = v; }
template <> __device__ inline void st4<u16>(u16* p, size_t i, float4 v) {
    ushort4 u = { f2b(v.x), f2b(v.y), f2b(v.z), f2b(v.w) };
    *(ushort4*)(p + i) = u;
}

__device__ inline float nlrelu(float z) { return (z > 0.f) ? -z : -0.01f * z; }  // -leaky_relu
__device__ inline float4 score4(float4 a, float4 b) {
    return make_float4(nlrelu(a.x + b.x), nlrelu(a.y + b.y), nlrelu(a.z + b.z), nlrelu(a.w + b.w));
}

// ---------------- weight pre-transpose (fp32) ----------------
__global__ void prep_w1t(const float* __restrict__ Wh, float* __restrict__ W1t) {
    int i = blockIdx.x * 256 + threadIdx.x;
    if (i >= 256 * 128) return;
    int n = i >> 7, k = i & 127;
    int h = n >> 6, f = n & 63;
    W1t[i] = Wh[h * (128 * 64) + k * 64 + f];
}
__global__ void prep_w2t(const float* __restrict__ Wo, float* __restrict__ W2t) {
    int i = blockIdx.x * 256 + threadIdx.x;
    if (i >= 64 * 256) return;
    int n = i >> 8, k = i & 255;
    W2t[i] = Wo[k * 64 + n];
}

__global__ void zero2(int* __restrict__ a, int* __restrict__ b, int n) {
    int i = blockIdx.x * 256 + threadIdx.x;
    if (i < n) { a[i] = 0; b[i] = 0; }
}

// ---------------- CSR build ----------------
__global__ void count_edges(const int* __restrict__ src, int* __restrict__ counts, int E, int N) {
    int e = blockIdx.x * 256 + threadIdx.x;
    if (e >= E) return;
    int s = src[e];
    s = ((unsigned)s < (unsigned)N) ? s : 0;
    atomicAdd(&counts[s], 1);
}

// multi-block scan: phase 1 — 1024-elem blocks, local exclusive prefix + block sum
__global__ __launch_bounds__(1024) void scan_p1(const int* __restrict__ counts, int* __restrict__ pre,
                                                int* __restrict__ bsum, int n) {
    const int t = threadIdx.x, lane = t & 63, w = t >> 6;
    __shared__ int wsum[16];
    int i = blockIdx.x * 1024 + t;
    int v = (i < n) ? counts[i] : 0;
    int orig = v;
    for (int d = 1; d < 64; d <<= 1) { int x = __shfl_up(v, d); if (lane >= d) v += x; }
    if (lane == 63) wsum[w] = v;
    __syncthreads();
    if (t == 0) {
        int acc = 0;
        for (int j = 0; j < 16; j++) { int tmp = wsum[j]; wsum[j] = acc; acc += tmp; }
        bsum[blockIdx.x] = acc;
    }
    __syncthreads();
    if (i < n) pre[i] = wsum[w] + (v - orig);
}
// phase 2 — scan block sums (single wave, serial; nb ~ 49)
__global__ void scan_p2(int* __restrict__ bsum, int nb) {
    if (threadIdx.x == 0) {
        int acc = 0;
        for (int j = 0; j < nb; j++) { int tmp = bsum[j]; bsum[j] = acc; acc += tmp; }
        bsum[nb] = acc;
    }
}
// phase 3 — add block offsets, emit row_start[0..n]
__global__ void scan_p3(const int* __restrict__ pre, const int* __restrict__ bsum,
                        int* __restrict__ row_start, int n, int nb) {
    int i = blockIdx.x * 256 + threadIdx.x;
    if (i < n) row_start[i] = pre[i] + bsum[i >> 10];
    else if (i == n) row_start[n] = bsum[nb];
}

__global__ void scatter_edges(const int* __restrict__ src, const int* __restrict__ dst,
                              const int* __restrict__ row_start, int* __restrict__ cursor,
                              int* __restrict__ edge_dst, int E, int N) {
    int e = blockIdx.x * 256 + threadIdx.x;
    if (e >= E) return;
    int s = src[e];
    s = ((unsigned)s < (unsigned)N) ? s : 0;
    int d = dst[e];
    d = ((unsigned)d < (unsigned)N) ? d : 0;
    int pos = atomicAdd(&cursor[s], 1);
    int idx = row_start[s] + pos;
    if ((unsigned)idx < (unsigned)E) edge_dst[idx] = d;
}

// ---------------- GEMM1 + fused s1/s2:  C[Mx256] = X[Mx128] @ W1t^T ----------------
template <typename OT>
__global__ __launch_bounds__(256) void gemm1(const float* __restrict__ X, const float* __restrict__ W1t,
                                             const float* __restrict__ attnH,
                                             OT* __restrict__ C, float* __restrict__ s1, float* __restrict__ s2,
                                             int M) {
    __shared__ float Xs[16 * 128];
    const int m0 = blockIdx.x * 16;
    const int t = threadIdx.x;
    float4* Xs4 = (float4*)Xs;
    if (m0 + 16 <= M) {
        const float4* g4 = (const float4*)(X + (size_t)m0 * 128);
        for (int i = t; i < 512; i += 256) Xs4[i] = g4[i];
    } else {
        for (int i = t; i < 2048; i += 256) {
            int r = i >> 7;
            Xs[i] = (m0 + r < M) ? X[(size_t)(m0 + r) * 128 + (i & 127)] : 0.f;
        }
    }
    __syncthreads();
    float acc[16];
#pragma unroll
    for (int r = 0; r < 16; r++) acc[r] = 0.f;
    const float4* w4p = (const float4*)(W1t + t * 128);
    for (int kq = 0; kq < 32; kq++) {
        float4 w = w4p[kq];
#pragma unroll
        for (int r = 0; r < 16; r++) {
            float4 xv = Xs4[r * 32 + kq];
            acc[r] += xv.x * w.x + xv.y * w.y + xv.z * w.z + xv.w * w.w;
        }
    }
#pragma unroll
    for (int r = 0; r < 16; r++)
        if (m0 + r < M) stH(C, (size_t)(m0 + r) * 256 + t, acc[r]);
    // fused attention scalars: wave w == head w, lane == feature f
    const int h = t >> 6, f = t & 63, lane = t & 63;
    const float a1v = attnH[h * 128 + f];
    const float a2v = attnH[h * 128 + 64 + f];
#pragma unroll
    for (int r = 0; r < 16; r++) {
        float p1 = acc[r] * a1v, p2 = acc[r] * a2v;
        for (int off = 32; off > 0; off >>= 1) { p1 += __shfl_down(p1, off); p2 += __shfl_down(p2, off); }
        if (lane == 0 && m0 + r < M) { s1[(m0 + r) * 4 + h] = p1; s2[(m0 + r) * 4 + h] = p2; }
    }
}

// ---------------- GEMM2 + fused s1b/s2b:  C[Mx64] = Hc[Mx256] @ W2t^T ----------------
template <typename IT, typename OT>
__global__ __launch_bounds__(256) void gemm2(const IT* __restrict__ Hc, const float* __restrict__ W2t,
                                             const float* __restrict__ attnO,
                                             OT* __restrict__ C, float* __restrict__ s1, float* __restrict__ s2,
                                             int M) {
    __shared__ float Xs[16 * 256];
    const int m0 = blockIdx.x * 16;
    const int t = threadIdx.x;
    for (int i = t; i < 4096; i += 256) {
        int r = i >> 8;
        Xs[i] = (m0 + r < M) ? ldH(Hc, (size_t)(m0 + r) * 256 + (i & 255)) : 0.f;
    }
    __syncthreads();
    const int n = t & 63, rq = t >> 6, lane = t & 63;
    float acc[4] = {0.f, 0.f, 0.f, 0.f};
    const float4* w4p = (const float4*)(W2t + n * 256);
    const float4* Xs4 = (const float4*)Xs;
    for (int kq = 0; kq < 64; kq++) {
        float4 w = w4p[kq];
#pragma unroll
        for (int i = 0; i < 4; i++) {
            float4 xv = Xs4[(rq * 4 + i) * 64 + kq];
            acc[i] += xv.x * w.x + xv.y * w.y + xv.z * w.z + xv.w * w.w;
        }
    }
#pragma unroll
    for (int i = 0; i < 4; i++) {
        int r = rq * 4 + i;
        if (m0 + r < M) stH(C, (size_t)(m0 + r) * 64 + n, acc[i]);
    }
    const float a1v = attnO[n], a2v = attnO[64 + n];
#pragma unroll
    for (int i = 0; i < 4; i++) {
        int m = m0 + rq * 4 + i;
        float p1 = acc[i] * a1v, p2 = acc[i] * a2v;
        for (int off = 32; off > 0; off >>= 1) { p1 += __shfl_down(p1, off); p2 += __shfl_down(p2, off); }
        if (lane == 0 && m < M) { s1[m] = p1; s2[m] = p2; }
    }
}

// ---------------- layer-1 aggregate: one wave per node, all 4 heads via float4 ----------------
template <typename HT, typename OT>
__global__ __launch_bounds__(256) void agg_l1(const int* __restrict__ rowst, const int* __restrict__ edged,
                                              const float* __restrict__ s1, const float* __restrict__ s2,
                                              const HT* __restrict__ H, OT* __restrict__ outp, int N, int E) {
    __shared__ float wls[4][256];
    __shared__ int dls[4][64];
    const int t = threadIdx.x, lane = t & 63, wave = t >> 6;
    const int node = blockIdx.x * 4 + wave;
    if (node >= N) return;
    int beg = rowst[node], end = rowst[node + 1];
    beg = max(0, min(beg, E)); end = max(beg, min(end, E));
    const int deg = end - beg;
    const int head = lane >> 4;
    if (deg == 0) { st4(outp, (size_t)node * 256 + lane * 4, make_float4(0.f, 0.f, 0.f, 0.f)); return; }
    const float4 s1v = *(const float4*)(s1 + (size_t)node * 4);

    float4 acc = make_float4(0.f, 0.f, 0.f, 0.f);
    if (deg <= 64) {
        int d = 0;
        if (lane < deg) { d = edged[beg + lane]; d = ((unsigned)d < (unsigned)N) ? d : 0; }
        dls[wave][lane] = d;
        float4 s2v = *(const float4*)(s2 + (size_t)d * 4);
        float4 sc = score4(s1v, s2v);
        if (lane >= deg) sc = make_float4(-3e38f, -3e38f, -3e38f, -3e38f);
        float4 m = sc;
#pragma unroll
        for (int off = 32; off > 0; off >>= 1) {
            m.x = fmaxf(m.x, __shfl_xor(m.x, off));
            m.y = fmaxf(m.y, __shfl_xor(m.y, off));
            m.z = fmaxf(m.z, __shfl_xor(m.z, off));
            m.w = fmaxf(m.w, __shfl_xor(m.w, off));
        }
        float4 ex = make_float4(0.f, 0.f, 0.f, 0.f);
        if (lane < deg) ex = make_float4(__expf(sc.x - m.x), __expf(sc.y - m.y),
                                         __expf(sc.z - m.z), __expf(sc.w - m.w));
        float4 sm = ex;
#pragma unroll
        for (int off = 32; off > 0; off >>= 1) {
            sm.x += __shfl_xor(sm.x, off);
            sm.y += __shfl_xor(sm.y, off);
            sm.z += __shfl_xor(sm.z, off);
            sm.w += __shfl_xor(sm.w, off);
        }
        float4 w4 = make_float4(ex.x / sm.x, ex.y / sm.y, ex.z / sm.z, ex.w / sm.w);
        *(float4*)&wls[wave][lane * 4] = w4;
        for (int e = 0; e < deg; e++) {
            float w = wls[wave][e * 4 + head];
            int dd = dls[wave][e];
            float4 h4 = ld4(H, (size_t)dd * 256 + lane * 4);
            acc.x += w * h4.x; acc.y += w * h4.y; acc.z += w * h4.z; acc.w += w * h4.w;
        }
    } else {
        // generic slow path (degree > 64) — lane-parallel max & sum, serial aggregate
        float4 m = make_float4(-3e38f, -3e38f, -3e38f, -3e38f);
        for (int e = beg + lane; e < end; e += 64) {
            int d = edged[e]; d = ((unsigned)d < (unsigned)N) ? d : 0;
            float4 sc = score4(s1v, *(const float4*)(s2 + (size_t)d * 4));
            m.x = fmaxf(m.x, sc.x); m.y = fmaxf(m.y, sc.y); m.z = fmaxf(m.z, sc.z); m.w = fmaxf(m.w, sc.w);
        }
#pragma unroll
        for (int off = 32; off > 0; off >>= 1) {
            m.x = fmaxf(m.x, __shfl_xor(m.x, off));
            m.y = fmaxf(m.y, __shfl_xor(m.y, off));
            m.z = fmaxf(m.z, __shfl_xor(m.z, off));
            m.w = fmaxf(m.w, __shfl_xor(m.w, off));
        }
        float4 sm = make_float4(0.f, 0.f, 0.f, 0.f);
        for (int e = beg + lane; e < end; e += 64) {
            int d = edged[e]; d = ((unsigned)d < (unsigned)N) ? d : 0;
            float4 sc = score4(s1v, *(const float4*)(s2 + (size_t)d * 4));
            sm.x += __expf(sc.x - m.x); sm.y += __expf(sc.y - m.y);
            sm.z += __expf(sc.z - m.z); sm.w += __expf(sc.w - m.w);
        }
#pragma unroll
        for (int off = 32; off > 0; off >>= 1) {
            sm.x += __shfl_xor(sm.x, off);
            sm.y += __shfl_xor(sm.y, off);
            sm.z += __shfl_xor(sm.z, off);
            sm.w += __shfl_xor(sm.w, off);
        }
        float4 inv = make_float4(1.f / sm.x, 1.f / sm.y, 1.f / sm.z, 1.f / sm.w);
        for (int e = beg; e < end; e++) {
            int dd = edged[e]; dd = ((unsigned)dd < (unsigned)N) ? dd : 0;
            float4 sc = score4(s1v, *(const float4*)(s2 + (size_t)dd * 4));
            float wv[4] = { __expf(sc.x - m.x) * inv.x, __expf(sc.y - m.y) * inv.y,
                            __expf(sc.z - m.z) * inv.z, __expf(sc.w - m.w) * inv.w };
            float w = (head == 0) ? wv[0] : (head == 1) ? wv[1] : (head == 2) ? wv[2] : wv[3];
            float4 h4 = ld4(H, (size_t)dd * 256 + lane * 4);
            acc.x += w * h4.x; acc.y += w * h4.y; acc.z += w * h4.z; acc.w += w * h4.w;
        }
    }
    // ELU
    acc.x = (acc.x > 0.f) ? acc.x : (__expf(acc.x) - 1.f);
    acc.y = (acc.y > 0.f) ? acc.y : (__expf(acc.y) - 1.f);
    acc.z = (acc.z > 0.f) ? acc.z : (__expf(acc.z) - 1.f);
    acc.w = (acc.w > 0.f) ? acc.w : (__expf(acc.w) - 1.f);
    st4(outp, (size_t)node * 256 + lane * 4, acc);
}

// ---------------- layer-2 aggregate: one wave per node, 64 features ----------------
template <typename HT>
__global__ __launch_bounds__(256) void agg_l2(const int* __restrict__ rowst, const int* __restrict__ edged,
                                              const float* __restrict__ s1, const float* __restrict__ s2,
                                              const HT* __restrict__ H, float* __restrict__ outp, int N, int E) {
    __shared__ float wls[4][64];
    __shared__ int dls[4][64];
    const int t = threadIdx.x, lane = t & 63, wave = t >> 6;
    const int node = blockIdx.x * 4 + wave;
    if (node >= N) return;
    int beg = rowst[node], end = rowst[node + 1];
    beg = max(0, min(beg, E)); end = max(beg, min(end, E));
    const int deg = end - beg;
    if (deg == 0) { outp[(size_t)node * 64 + lane] = 0.f; return; }
    const float s1v = s1[node];

    float acc = 0.f;
    if (deg <= 64) {
        int d = 0;
        if (lane < deg) { d = edged[beg + lane]; d = ((unsigned)d < (unsigned)N) ? d : 0; }
        dls[wave][lane] = d;
        float z = s1v + s2[d];
        float sc = (lane < deg) ? nlrelu(z) : -3e38f;
        float m = sc;
#pragma unroll
        for (int off = 32; off > 0; off >>= 1) m = fmaxf(m, __shfl_xor(m, off));
        float ex = (lane < deg) ? __expf(sc - m) : 0.f;
        float sm = ex;
#pragma unroll
        for (int off = 32; off > 0; off >>= 1) sm += __shfl_xor(sm, off);
        wls[wave][lane] = ex / sm;
        for (int e = 0; e < deg; e++)
            acc += wls[wave][e] * ldH(H, (size_t)dls[wave][e] * 64 + lane);
    } else {
        float m = -3e38f;
        for (int e = beg + lane; e < end; e += 64) {
            int d = edged[e]; d = ((unsigned)d < (unsigned)N) ? d : 0;
            m = fmaxf(m, nlrelu(s1v + s2[d]));
        }
#pragma unroll
        for (int off = 32; off > 0; off >>= 1) m = fmaxf(m, __shfl_xor(m, off));
        float sm = 0.f;
        for (int e = beg + lane; e < end; e += 64) {
            int d = edged[e]; d = ((unsigned)d < (unsigned)N) ? d : 0;
            sm += __expf(nlrelu(s1v + s2[d]) - m);
        }
#pragma unroll
        for (int off = 32; off > 0; off >>= 1) sm += __shfl_xor(sm, off);
        float inv = 1.f / sm;
        for (int e = beg; e < end; e++) {
            int dd = edged[e]; dd = ((unsigned)dd < (unsigned)N) ? dd : 0;
            float w = __expf(nlrelu(s1v + s2[dd]) - m) * inv;
            acc += w * ldH(H, (size_t)dd * 64 + lane);
        }
    }
    outp[(size_t)node * 64 + lane] = acc;
}

// ---------------- host pipeline ----------------
template <typename HT1, typename HTC, typename HT2>
static void run_pipeline(const float* x, const int* srcp, const int* dstp,
                         const float* Wh, const float* attnH, const float* Wo, const float* attnO,
                         float* out, char* base, int N, int E, hipStream_t stream) {
    size_t off = 0;
    auto take = [&](size_t b) { void* p = base + off; off += (b + 255) & ~(size_t)255; return p; };
    float* W1t    = (float*)take(256 * 128 * 4);
    float* W2t    = (float*)take(64 * 256 * 4);
    int*   counts = (int*)  take((size_t)N * 4);
    int*   cursor = (int*)  take((size_t)N * 4);
    int*   rowst  = (int*)  take((size_t)(N + 1) * 4);
    int*   edged  = (int*)  take((size_t)E * 4);
    float* s1     = (float*)take((size_t)N * 4 * 4);
    float* s2     = (float*)take((size_t)N * 4 * 4);
    float* s1b    = (float*)take((size_t)N * 4);
    float* s2b    = (float*)take((size_t)N * 4);
    int*   pre    = (int*)  take((size_t)N * 4);        // scan temp (reuses budget)
    int*   bsum   = (int*)  take(4096);
    HT1*   H1     = (HT1*)  take((size_t)N * 256 * sizeof(HT1));
    HTC*   hcat   = (HTC*)  take((size_t)N * 256 * sizeof(HTC));
    HT2*   H2     = (HT2*)  take((size_t)N * 64 * sizeof(HT2));

    prep_w1t<<<128, 256, 0, stream>>>(Wh, W1t);
    prep_w2t<<<64, 256, 0, stream>>>(Wo, W2t);
    zero2<<<(N + 255) / 256, 256, 0, stream>>>(counts, cursor, N);

    count_edges<<<(E + 255) / 256, 256, 0, stream>>>(srcp, counts, E, N);
    const int nb = (N + 1023) / 1024;
    scan_p1<<<nb, 1024, 0, stream>>>(counts, pre, bsum, N);
    scan_p2<<<1, 64, 0, stream>>>(bsum, nb);
    scan_p3<<<(N + 256) / 256, 256, 0, stream>>>(pre, bsum, rowst, N, nb);
    scatter_edges<<<(E + 255) / 256, 256, 0, stream>>>(srcp, dstp, rowst, cursor, edged, E, N);

    const int rowBlocks = (N + 15) / 16;
    gemm1<<<rowBlocks, 256, 0, stream>>>(x, W1t, attnH, H1, s1, s2, N);
    agg_l1<<<(N + 3) / 4, 256, 0, stream>>>(rowst, edged, s1, s2, H1, hcat, N, E);

    gemm2<<<rowBlocks, 256, 0, stream>>>(hcat, W2t, attnO, H2, s1b, s2b, N);
    agg_l2<<<(N + 3) / 4, 256, 0, stream>>>(rowst, edged, s1b, s2b, H2, out, N, E);
}

extern "C" void kernel_launch(void* const* d_in, const int* in_sizes, int n_in,
                              void* d_out, int out_size, void* d_ws, size_t ws_size,
                              hipStream_t stream) {
    const float* x     = (const float*)d_in[0];
    const int*   ei    = (const int*)d_in[1];     // [2][E] int32
    const float* Wh    = (const float*)d_in[2];
    const float* attnH = (const float*)d_in[3];
    const float* Wo    = (const float*)d_in[4];
    const float* attnO = (const float*)d_in[5];
    float* out         = (float*)d_out;

    const int N = in_sizes[0] / 128;    // 50000
    const int E = in_sizes[1] / 2;      // 800000
    const int* srcp = ei;
    const int* dstp = ei + E;

    auto al = [](size_t b) { return (b + 255) & ~(size_t)255; };
    size_t misc = al(256 * 128 * 4) + al(64 * 256 * 4) + 2 * al((size_t)N * 4) +
                  al((size_t)(N + 1) * 4) + al((size_t)E * 4) +
                  2 * al((size_t)N * 16) + 2 * al((size_t)N * 4) +
                  al((size_t)N * 4) + al(4096);
    size_t h256f = al((size_t)N * 256 * 4), h256b = al((size_t)N * 256 * 2);
    size_t h64f = al((size_t)N * 64 * 4);

    char* ws = (char*)d_ws;
    if (ws_size >= misc + 2 * h256f + h64f)          // plan A: all fp32
        run_pipeline<float, float, float>(x, srcp, dstp, Wh, attnH, Wo, attnO, out, ws, N, E, stream);
    else if (ws_size >= misc + h256f + h256b + h64f) // plan B: hcat bf16
        run_pipeline<float, u16, float>(x, srcp, dstp, Wh, attnH, Wo, attnO, out, ws, N, E, stream);
    else if (ws_size >= misc + 2 * h256b + h64f)     // plan C: H1+hcat bf16
        run_pipeline<u16, u16, float>(x, srcp, dstp, Wh, attnH, Wo, attnO, out, ws, N, E, stream);
    else                                             // plan D: all bf16
        run_pipeline<u16, u16, u16>(x, srcp, dstp, Wh, attnH, Wo, attnO, out, ws, N, E, stream);
}

// Round 5
// 385.935 us; speedup vs baseline: 2.1252x; 1.4400x over previous
//
#include <hip/hip_runtime.h>

typedef unsigned short u16;
typedef __attribute__((ext_vector_type(8))) short bf16x8;
typedef __attribute__((ext_vector_type(4))) float f32x4;

__device__ inline float b2f(u16 u) {
    union { unsigned int i; float f; } c; c.i = ((unsigned int)u) << 16; return c.f;
}
__device__ inline u16 f2b(float f) {
    union { float f; unsigned int i; } c; c.f = f;
    unsigned int i = c.i;
    i += 0x7fffu + ((i >> 16) & 1u);   // RTNE
    return (u16)(i >> 16);
}

// scalar generic storage
template <typename T> __device__ inline float ldH(const T* p, size_t i);
template <> __device__ inline float ldH<float>(const float* p, size_t i) { return p[i]; }
template <> __device__ inline float ldH<u16>(const u16* p, size_t i) { return b2f(p[i]); }
template <typename T> __device__ inline void stH(T* p, size_t i, float v);
template <> __device__ inline void stH<float>(float* p, size_t i, float v) { p[i] = v; }
template <> __device__ inline void stH<u16>(u16* p, size_t i, float v) { p[i] = f2b(v); }

// vector4 generic storage
template <typename T> __device__ inline float4 ld4(const T* p, size_t i);
template <> __device__ inline float4 ld4<float>(const float* p, size_t i) { return *(const float4*)(p + i); }
template <> __device__ inline float4 ld4<u16>(const u16* p, size_t i) {
    ushort4 u = *(const ushort4*)(p + i);
    return make_float4(b2f(u.x), b2f(u.y), b2f(u.z), b2f(u.w));
}

__device__ inline float nlrelu(float z) { return (z > 0.f) ? -z : -0.01f * z; }  // -leaky_relu
__device__ inline float4 score4(float4 a, float4 b) {
    return make_float4(nlrelu(a.x + b.x), nlrelu(a.y + b.y), nlrelu(a.z + b.z), nlrelu(a.w + b.w));
}

// ---------------- weight frag-order split decomposition ----------------
// B1h/B1l[((nt*4+kg)*64+lane)*8 + j] = hi/lo of W_heads[h][k][f], n=nt*16+(lane&15), h=n>>6, f=n&63,
//   k = kg*32 + (lane>>4)*8 + j
__global__ void prep_w1frag(const float* __restrict__ Wh, u16* __restrict__ B1h, u16* __restrict__ B1l) {
    int i = blockIdx.x * 256 + threadIdx.x;          // 32768
    if (i >= 32768) return;
    int j = i & 7, lane = (i >> 3) & 63, kg = (i >> 9) & 3, nt = i >> 11;
    int n = nt * 16 + (lane & 15);
    int k = kg * 32 + ((lane >> 4) << 3) + j;
    float val = Wh[(n >> 6) * (128 * 64) + k * 64 + (n & 63)];
    u16 hi = f2b(val);
    B1h[i] = hi;
    B1l[i] = f2b(val - b2f(hi));
}
// B2: n = nt*16+(lane&15) in [0,64), k = kg*32+(lane>>4)*8+j in [0,256); val = W_out[k][n]
__global__ void prep_w2frag(const float* __restrict__ Wo, u16* __restrict__ B2h, u16* __restrict__ B2l) {
    int i = blockIdx.x * 256 + threadIdx.x;          // 16384
    if (i >= 16384) return;
    int j = i & 7, lane = (i >> 3) & 63, kg = (i >> 9) & 7, nt = i >> 12;
    int n = nt * 16 + (lane & 15);
    int k = kg * 32 + ((lane >> 4) << 3) + j;
    float val = Wo[k * 64 + n];
    u16 hi = f2b(val);
    B2h[i] = hi;
    B2l[i] = f2b(val - b2f(hi));
}

__global__ void zero2(int* __restrict__ a, int* __restrict__ b, int n) {
    int i = blockIdx.x * 256 + threadIdx.x;
    if (i < n) { a[i] = 0; b[i] = 0; }
}

// ---------------- CSR build ----------------
__global__ void count_edges(const int* __restrict__ src, int* __restrict__ counts, int E, int N) {
    int e = blockIdx.x * 256 + threadIdx.x;
    if (e >= E) return;
    int s = src[e];
    s = ((unsigned)s < (unsigned)N) ? s : 0;
    atomicAdd(&counts[s], 1);
}

__global__ __launch_bounds__(1024) void scan_p1(const int* __restrict__ counts, int* __restrict__ pre,
                                                int* __restrict__ bsum, int n) {
    const int t = threadIdx.x, lane = t & 63, w = t >> 6;
    __shared__ int wsum[16];
    int i = blockIdx.x * 1024 + t;
    int v = (i < n) ? counts[i] : 0;
    int orig = v;
    for (int d = 1; d < 64; d <<= 1) { int x = __shfl_up(v, d); if (lane >= d) v += x; }
    if (lane == 63) wsum[w] = v;
    __syncthreads();
    if (t == 0) {
        int acc = 0;
        for (int j = 0; j < 16; j++) { int tmp = wsum[j]; wsum[j] = acc; acc += tmp; }
        bsum[blockIdx.x] = acc;
    }
    __syncthreads();
    if (i < n) pre[i] = wsum[w] + (v - orig);
}
__global__ void scan_p2(int* __restrict__ bsum, int nb) {
    if (threadIdx.x == 0) {
        int acc = 0;
        for (int j = 0; j < nb; j++) { int tmp = bsum[j]; bsum[j] = acc; acc += tmp; }
        bsum[nb] = acc;
    }
}
__global__ void scan_p3(const int* __restrict__ pre, const int* __restrict__ bsum,
                        int* __restrict__ row_start, int n, int nb) {
    int i = blockIdx.x * 256 + threadIdx.x;
    if (i < n) row_start[i] = pre[i] + bsum[i >> 10];
    else if (i == n) row_start[n] = bsum[nb];
}

__global__ void scatter_edges(const int* __restrict__ src, const int* __restrict__ dst,
                              const int* __restrict__ row_start, int* __restrict__ cursor,
                              int* __restrict__ edge_dst, int E, int N) {
    int e = blockIdx.x * 256 + threadIdx.x;
    if (e >= E) return;
    int s = src[e];
    s = ((unsigned)s < (unsigned)N) ? s : 0;
    int d = dst[e];
    d = ((unsigned)d < (unsigned)N) ? d : 0;
    int pos = atomicAdd(&cursor[s], 1);
    int idx = row_start[s] + pos;
    if ((unsigned)idx < (unsigned)E) edge_dst[idx] = d;
}

// ---------------- GEMM1 (split-bf16 MFMA): H1[Mx256] = X[Mx128] @ W1^T, fused s1/s2 ----------------
template <typename HT1>
__global__ __launch_bounds__(256) void gemm1_mfma(const float* __restrict__ X,
        const u16* __restrict__ B1h, const u16* __restrict__ B1l,
        const float* __restrict__ attnH,
        HT1* __restrict__ H1, float* __restrict__ s1, float* __restrict__ s2, int M) {
    const int lane = threadIdx.x & 63, wave = threadIdx.x >> 6;
    const int row0 = (blockIdx.x * 4 + wave) * 16;
    if (row0 >= M) return;
    const int mrow = row0 + (lane & 15);
    const int koff = (lane >> 4) * 8;
    const float* aptr = X + (size_t)mrow * 128 + koff;

    f32x4 acc[16];
#pragma unroll
    for (int c = 0; c < 16; c++) acc[c] = (f32x4){0.f, 0.f, 0.f, 0.f};

#pragma unroll
    for (int kg = 0; kg < 4; kg++) {
        float av[8];
        *(float4*)av       = *(const float4*)(aptr + kg * 32);
        *(float4*)(av + 4) = *(const float4*)(aptr + kg * 32 + 4);
        bf16x8 ah, al;
#pragma unroll
        for (int j = 0; j < 8; j++) {
            u16 h = f2b(av[j]);
            ah[j] = (short)h;
            al[j] = (short)f2b(av[j] - b2f(h));
        }
#pragma unroll
        for (int nt = 0; nt < 16; nt++) {
            const size_t bidx = (size_t)(((nt << 2) + kg) * 64 + lane) * 8;
            bf16x8 bh = *(const bf16x8*)(B1h + bidx);
            bf16x8 bl = *(const bf16x8*)(B1l + bidx);
            acc[nt] = __builtin_amdgcn_mfma_f32_16x16x32_bf16(ah, bh, acc[nt], 0, 0, 0);
            acc[nt] = __builtin_amdgcn_mfma_f32_16x16x32_bf16(al, bh, acc[nt], 0, 0, 0);
            acc[nt] = __builtin_amdgcn_mfma_f32_16x16x32_bf16(ah, bl, acc[nt], 0, 0, 0);
        }
    }
    // epilogue: C row=(lane>>4)*4+r, col=nt*16+(lane&15); store H1 + fused s1/s2
    const int rbase = (lane >> 4) * 4;
    const int colq = lane & 15;
#pragma unroll
    for (int h = 0; h < 4; h++) {
        float s1a[4] = {0.f, 0.f, 0.f, 0.f}, s2a[4] = {0.f, 0.f, 0.f, 0.f};
#pragma unroll
        for (int q = 0; q < 4; q++) {
            const int nt = h * 4 + q;
            const int col = nt * 16 + colq;
            const float a1v = attnH[h * 128 + (col & 63)];
            const float a2v = attnH[h * 128 + 64 + (col & 63)];
#pragma unroll
            for (int r = 0; r < 4; r++) {
                float c = acc[nt][r];
                stH(H1, (size_t)(row0 + rbase + r) * 256 + col, c);
                s1a[r] += c * a1v;
                s2a[r] += c * a2v;
            }
        }
#pragma unroll
        for (int off = 1; off < 16; off <<= 1)
#pragma unroll
            for (int r = 0; r < 4; r++) {
                s1a[r] += __shfl_xor(s1a[r], off);
                s2a[r] += __shfl_xor(s2a[r], off);
            }
        if (colq == 0)
#pragma unroll
            for (int r = 0; r < 4; r++) {
                s1[(size_t)(row0 + rbase + r) * 4 + h] = s1a[r];
                s2[(size_t)(row0 + rbase + r) * 4 + h] = s2a[r];
            }
    }
}

// ---------------- GEMM2 (split-bf16 MFMA): H2[Mx64] = Hc[Mx256] @ W2^T, fused s1b/s2b ----------------
template <bool HCL, typename HT2>
__global__ __launch_bounds__(256) void gemm2_mfma(const u16* __restrict__ Ahp, const u16* __restrict__ Alp,
        const u16* __restrict__ B2h, const u16* __restrict__ B2l,
        const float* __restrict__ attnO,
        HT2* __restrict__ H2, float* __restrict__ s1b, float* __restrict__ s2b, int M) {
    const int lane = threadIdx.x & 63, wave = threadIdx.x >> 6;
    const int row0 = (blockIdx.x * 4 + wave) * 16;
    if (row0 >= M) return;
    const int mrow = row0 + (lane & 15);
    const int koff = (lane >> 4) * 8;
    const u16* ah_p = Ahp + (size_t)mrow * 256 + koff;
    const u16* al_p = Alp + (size_t)mrow * 256 + koff;

    f32x4 acc[4];
#pragma unroll
    for (int c = 0; c < 4; c++) acc[c] = (f32x4){0.f, 0.f, 0.f, 0.f};

#pragma unroll
    for (int kg = 0; kg < 8; kg++) {
        bf16x8 ah = *(const bf16x8*)(ah_p + kg * 32);
        bf16x8 al;
        if (HCL) al = *(const bf16x8*)(al_p + kg * 32);
#pragma unroll
        for (int nt = 0; nt < 4; nt++) {
            const size_t bidx = (size_t)(((nt << 3) + kg) * 64 + lane) * 8;
            bf16x8 bh = *(const bf16x8*)(B2h + bidx);
            bf16x8 bl = *(const bf16x8*)(B2l + bidx);
            acc[nt] = __builtin_amdgcn_mfma_f32_16x16x32_bf16(ah, bh, acc[nt], 0, 0, 0);
            if (HCL) acc[nt] = __builtin_amdgcn_mfma_f32_16x16x32_bf16(al, bh, acc[nt], 0, 0, 0);
            acc[nt] = __builtin_amdgcn_mfma_f32_16x16x32_bf16(ah, bl, acc[nt], 0, 0, 0);
        }
    }
    const int rbase = (lane >> 4) * 4;
    const int colq = lane & 15;
    float s1a[4] = {0.f, 0.f, 0.f, 0.f}, s2a[4] = {0.f, 0.f, 0.f, 0.f};
#pragma unroll
    for (int nt = 0; nt < 4; nt++) {
        const int col = nt * 16 + colq;
        const float a1v = attnO[col];
        const float a2v = attnO[64 + col];
#pragma unroll
        for (int r = 0; r < 4; r++) {
            float c = acc[nt][r];
            stH(H2, (size_t)(row0 + rbase + r) * 64 + col, c);
            s1a[r] += c * a1v;
            s2a[r] += c * a2v;
        }
    }
#pragma unroll
    for (int off = 1; off < 16; off <<= 1)
#pragma unroll
        for (int r = 0; r < 4; r++) {
            s1a[r] += __shfl_xor(s1a[r], off);
            s2a[r] += __shfl_xor(s2a[r], off);
        }
    if (colq == 0)
#pragma unroll
        for (int r = 0; r < 4; r++) {
            s1b[row0 + rbase + r] = s1a[r];
            s2b[row0 + rbase + r] = s2a[r];
        }
}

// ---------------- layer-1 aggregate: one wave per node, 4 heads via float4; hcat -> bf16 hi(/lo) ----------------
template <typename HT, bool WL>
__global__ __launch_bounds__(256) void agg_l1(const int* __restrict__ rowst, const int* __restrict__ edged,
                                              const float* __restrict__ s1, const float* __restrict__ s2,
                                              const HT* __restrict__ H,
                                              u16* __restrict__ hcat_h, u16* __restrict__ hcat_l,
                                              int N, int E) {
    __shared__ float wls[4][256];
    __shared__ int dls[4][64];
    const int t = threadIdx.x, lane = t & 63, wave = t >> 6;
    const int node = blockIdx.x * 4 + wave;
    if (node >= N) return;
    int beg = rowst[node], end = rowst[node + 1];
    beg = max(0, min(beg, E)); end = max(beg, min(end, E));
    const int deg = end - beg;
    const int head = lane >> 4;
    const size_t obase = (size_t)node * 256 + lane * 4;
    if (deg == 0) {
        ushort4 z = {0, 0, 0, 0};
        *(ushort4*)(hcat_h + obase) = z;
        if (WL) *(ushort4*)(hcat_l + obase) = z;
        return;
    }
    const float4 s1v = *(const float4*)(s1 + (size_t)node * 4);

    float4 acc = make_float4(0.f, 0.f, 0.f, 0.f);
    if (deg <= 64) {
        int d = 0;
        if (lane < deg) { d = edged[beg + lane]; d = ((unsigned)d < (unsigned)N) ? d : 0; }
        dls[wave][lane] = d;
        float4 s2v = *(const float4*)(s2 + (size_t)d * 4);
        float4 sc = score4(s1v, s2v);
        if (lane >= deg) sc = make_float4(-3e38f, -3e38f, -3e38f, -3e38f);
        float4 m = sc;
#pragma unroll
        for (int off = 32; off > 0; off >>= 1) {
            m.x = fmaxf(m.x, __shfl_xor(m.x, off));
            m.y = fmaxf(m.y, __shfl_xor(m.y, off));
            m.z = fmaxf(m.z, __shfl_xor(m.z, off));
            m.w = fmaxf(m.w, __shfl_xor(m.w, off));
        }
        float4 ex = make_float4(0.f, 0.f, 0.f, 0.f);
        if (lane < deg) ex = make_float4(__expf(sc.x - m.x), __expf(sc.y - m.y),
                                         __expf(sc.z - m.z), __expf(sc.w - m.w));
        float4 sm = ex;
#pragma unroll
        for (int off = 32; off > 0; off >>= 1) {
            sm.x += __shfl_xor(sm.x, off);
            sm.y += __shfl_xor(sm.y, off);
            sm.z += __shfl_xor(sm.z, off);
            sm.w += __shfl_xor(sm.w, off);
        }
        float4 w4 = make_float4(ex.x / sm.x, ex.y / sm.y, ex.z / sm.z, ex.w / sm.w);
        *(float4*)&wls[wave][lane * 4] = w4;
        for (int e = 0; e < deg; e++) {
            float w = wls[wave][e * 4 + head];
            int dd = dls[wave][e];
            float4 h4 = ld4(H, (size_t)dd * 256 + lane * 4);
            acc.x += w * h4.x; acc.y += w * h4.y; acc.z += w * h4.z; acc.w += w * h4.w;
        }
    } else {
        float4 m = make_float4(-3e38f, -3e38f, -3e38f, -3e38f);
        for (int e = beg + lane; e < end; e += 64) {
            int d = edged[e]; d = ((unsigned)d < (unsigned)N) ? d : 0;
            float4 sc = score4(s1v, *(const float4*)(s2 + (size_t)d * 4));
            m.x = fmaxf(m.x, sc.x); m.y = fmaxf(m.y, sc.y); m.z = fmaxf(m.z, sc.z); m.w = fmaxf(m.w, sc.w);
        }
#pragma unroll
        for (int off = 32; off > 0; off >>= 1) {
            m.x = fmaxf(m.x, __shfl_xor(m.x, off));
            m.y = fmaxf(m.y, __shfl_xor(m.y, off));
            m.z = fmaxf(m.z, __shfl_xor(m.z, off));
            m.w = fmaxf(m.w, __shfl_xor(m.w, off));
        }
        float4 sm = make_float4(0.f, 0.f, 0.f, 0.f);
        for (int e = beg + lane; e < end; e += 64) {
            int d = edged[e]; d = ((unsigned)d < (unsigned)N) ? d : 0;
            float4 sc = score4(s1v, *(const float4*)(s2 + (size_t)d * 4));
            sm.x += __expf(sc.x - m.x); sm.y += __expf(sc.y - m.y);
            sm.z += __expf(sc.z - m.z); sm.w += __expf(sc.w - m.w);
        }
#pragma unroll
        for (int off = 32; off > 0; off >>= 1) {
            sm.x += __shfl_xor(sm.x, off);
            sm.y += __shfl_xor(sm.y, off);
            sm.z += __shfl_xor(sm.z, off);
            sm.w += __shfl_xor(sm.w, off);
        }
        float4 inv = make_float4(1.f / sm.x, 1.f / sm.y, 1.f / sm.z, 1.f / sm.w);
        for (int e = beg; e < end; e++) {
            int dd = edged[e]; dd = ((unsigned)dd < (unsigned)N) ? dd : 0;
            float4 sc = score4(s1v, *(const float4*)(s2 + (size_t)dd * 4));
            float wv[4] = { __expf(sc.x - m.x) * inv.x, __expf(sc.y - m.y) * inv.y,
                            __expf(sc.z - m.z) * inv.z, __expf(sc.w - m.w) * inv.w };
            float w = (head == 0) ? wv[0] : (head == 1) ? wv[1] : (head == 2) ? wv[2] : wv[3];
            float4 h4 = ld4(H, (size_t)dd * 256 + lane * 4);
            acc.x += w * h4.x; acc.y += w * h4.y; acc.z += w * h4.z; acc.w += w * h4.w;
        }
    }
    acc.x = (acc.x > 0.f) ? acc.x : (__expf(acc.x) - 1.f);
    acc.y = (acc.y > 0.f) ? acc.y : (__expf(acc.y) - 1.f);
    acc.z = (acc.z > 0.f) ? acc.z : (__expf(acc.z) - 1.f);
    acc.w = (acc.w > 0.f) ? acc.w : (__expf(acc.w) - 1.f);
    ushort4 hv, lv;
    hv.x = f2b(acc.x); hv.y = f2b(acc.y); hv.z = f2b(acc.z); hv.w = f2b(acc.w);
    *(ushort4*)(hcat_h + obase) = hv;
    if (WL) {
        lv.x = f2b(acc.x - b2f(hv.x)); lv.y = f2b(acc.y - b2f(hv.y));
        lv.z = f2b(acc.z - b2f(hv.z)); lv.w = f2b(acc.w - b2f(hv.w));
        *(ushort4*)(hcat_l + obase) = lv;
    }
}

// ---------------- layer-2 aggregate: one wave per node, 64 features ----------------
template <typename HT>
__global__ __launch_bounds__(256) void agg_l2(const int* __restrict__ rowst, const int* __restrict__ edged,
                                              const float* __restrict__ s1, const float* __restrict__ s2,
                                              const HT* __restrict__ H, float* __restrict__ outp, int N, int E) {
    __shared__ float wls[4][64];
    __shared__ int dls[4][64];
    const int t = threadIdx.x, lane = t & 63, wave = t >> 6;
    const int node = blockIdx.x * 4 + wave;
    if (node >= N) return;
    int beg = rowst[node], end = rowst[node + 1];
    beg = max(0, min(beg, E)); end = max(beg, min(end, E));
    const int deg = end - beg;
    if (deg == 0) { outp[(size_t)node * 64 + lane] = 0.f; return; }
    const float s1v = s1[node];

    float acc = 0.f;
    if (deg <= 64) {
        int d = 0;
        if (lane < deg) { d = edged[beg + lane]; d = ((unsigned)d < (unsigned)N) ? d : 0; }
        dls[wave][lane] = d;
        float z = s1v + s2[d];
        float sc = (lane < deg) ? nlrelu(z) : -3e38f;
        float m = sc;
#pragma unroll
        for (int off = 32; off > 0; off >>= 1) m = fmaxf(m, __shfl_xor(m, off));
        float ex = (lane < deg) ? __expf(sc - m) : 0.f;
        float sm = ex;
#pragma unroll
        for (int off = 32; off > 0; off >>= 1) sm += __shfl_xor(sm, off);
        wls[wave][lane] = ex / sm;
        for (int e = 0; e < deg; e++)
            acc += wls[wave][e] * ldH(H, (size_t)dls[wave][e] * 64 + lane);
    } else {
        float m = -3e38f;
        for (int e = beg + lane; e < end; e += 64) {
            int d = edged[e]; d = ((unsigned)d < (unsigned)N) ? d : 0;
            m = fmaxf(m, nlrelu(s1v + s2[d]));
        }
#pragma unroll
        for (int off = 32; off > 0; off >>= 1) m = fmaxf(m, __shfl_xor(m, off));
        float sm = 0.f;
        for (int e = beg + lane; e < end; e += 64) {
            int d = edged[e]; d = ((unsigned)d < (unsigned)N) ? d : 0;
            sm += __expf(nlrelu(s1v + s2[d]) - m);
        }
#pragma unroll
        for (int off = 32; off > 0; off >>= 1) sm += __shfl_xor(sm, off);
        float inv = 1.f / sm;
        for (int e = beg; e < end; e++) {
            int dd = edged[e]; dd = ((unsigned)dd < (unsigned)N) ? dd : 0;
            float w = __expf(nlrelu(s1v + s2[dd]) - m) * inv;
            acc += w * ldH(H, (size_t)dd * 64 + lane);
        }
    }
    outp[(size_t)node * 64 + lane] = acc;
}

// ---------------- host pipeline ----------------
template <typename HT1, bool WL>
static void run_pipeline(const float* x, const int* srcp, const int* dstp,
                         const float* Wh, const float* attnH, const float* Wo, const float* attnO,
                         float* out, char* base, int N, int E, hipStream_t stream) {
    size_t off = 0;
    auto take = [&](size_t b) { void* p = base + off; off += (b + 255) & ~(size_t)255; return p; };
    u16*   B1h    = (u16*)  take(32768 * 2);
    u16*   B1l    = (u16*)  take(32768 * 2);
    u16*   B2h    = (u16*)  take(16384 * 2);
    u16*   B2l    = (u16*)  take(16384 * 2);
    int*   counts = (int*)  take((size_t)N * 4);
    int*   cursor = (int*)  take((size_t)N * 4);
    int*   rowst  = (int*)  take((size_t)(N + 1) * 4);
    int*   edged  = (int*)  take((size_t)E * 4);
    int*   pre    = (int*)  take((size_t)N * 4);
    int*   bsum   = (int*)  take(4096);
    float* s1     = (float*)take((size_t)N * 4 * 4);
    float* s2     = (float*)take((size_t)N * 4 * 4);
    float* s1b    = (float*)take((size_t)N * 4);
    float* s2b    = (float*)take((size_t)N * 4);
    HT1*   H1     = (HT1*)  take((size_t)N * 256 * sizeof(HT1));
    u16*   hcat_h = (u16*)  take((size_t)N * 256 * 2);
    u16*   hcat_l = WL ? (u16*)take((size_t)N * 256 * 2) : hcat_h;
    float* H2     = (float*)take((size_t)N * 64 * 4);

    prep_w1frag<<<128, 256, 0, stream>>>(Wh, B1h, B1l);
    prep_w2frag<<<64, 256, 0, stream>>>(Wo, B2h, B2l);
    zero2<<<(N + 255) / 256, 256, 0, stream>>>(counts, cursor, N);

    count_edges<<<(E + 255) / 256, 256, 0, stream>>>(srcp, counts, E, N);
    const int nb = (N + 1023) / 1024;
    scan_p1<<<nb, 1024, 0, stream>>>(counts, pre, bsum, N);
    scan_p2<<<1, 64, 0, stream>>>(bsum, nb);
    scan_p3<<<(N + 256) / 256, 256, 0, stream>>>(pre, bsum, rowst, N, nb);
    scatter_edges<<<(E + 255) / 256, 256, 0, stream>>>(srcp, dstp, rowst, cursor, edged, E, N);

    const int gemmGrid = ((N + 15) / 16 + 3) / 4;
    gemm1_mfma<<<gemmGrid, 256, 0, stream>>>(x, B1h, B1l, attnH, H1, s1, s2, N);
    agg_l1<HT1, WL><<<(N + 3) / 4, 256, 0, stream>>>(rowst, edged, s1, s2, H1, hcat_h, hcat_l, N, E);

    gemm2_mfma<WL, float><<<gemmGrid, 256, 0, stream>>>(hcat_h, hcat_l, B2h, B2l, attnO, H2, s1b, s2b, N);
    agg_l2<<<(N + 3) / 4, 256, 0, stream>>>(rowst, edged, s1b, s2b, H2, out, N, E);
}

extern "C" void kernel_launch(void* const* d_in, const int* in_sizes, int n_in,
                              void* d_out, int out_size, void* d_ws, size_t ws_size,
                              hipStream_t stream) {
    const float* x     = (const float*)d_in[0];
    const int*   ei    = (const int*)d_in[1];     // [2][E] int32
    const float* Wh    = (const float*)d_in[2];
    const float* attnH = (const float*)d_in[3];
    const float* Wo    = (const float*)d_in[4];
    const float* attnO = (const float*)d_in[5];
    float* out         = (float*)d_out;

    const int N = in_sizes[0] / 128;    // 50000
    const int E = in_sizes[1] / 2;      // 800000
    const int* srcp = ei;
    const int* dstp = ei + E;

    auto al = [](size_t b) { return (b + 255) & ~(size_t)255; };
    size_t misc = 2 * al(32768 * 2) + 2 * al(16384 * 2) +
                  3 * al((size_t)N * 4) + al((size_t)(N + 1) * 4) + al((size_t)E * 4) + al(4096) +
                  2 * al((size_t)N * 16) + 2 * al((size_t)N * 4);
    size_t h256f = al((size_t)N * 256 * 4), h256b = al((size_t)N * 256 * 2);
    size_t h64f = al((size_t)N * 64 * 4);

    char* ws = (char*)d_ws;
    if (ws_size >= misc + h256f + 2 * h256b + h64f)       // plan X: H1 fp32, hcat hi+lo (~121.5 MB)
        run_pipeline<float, true>(x, srcp, dstp, Wh, attnH, Wo, attnO, out, ws, N, E, stream);
    else if (ws_size >= misc + h256f + h256b + h64f)      // plan Y: H1 fp32, hcat hi only (~96 MB)
        run_pipeline<float, false>(x, srcp, dstp, Wh, attnH, Wo, attnO, out, ws, N, E, stream);
    else                                                  // plan Z: H1 bf16, hcat hi only (~70 MB)
        run_pipeline<u16, false>(x, srcp, dstp, Wh, attnH, Wo, attnO, out, ws, N, E, stream);
}

// Round 6
// 317.182 us; speedup vs baseline: 2.5859x; 1.2168x over previous
//
#include <hip/hip_runtime.h>

typedef unsigned short u16;
typedef __attribute__((ext_vector_type(8))) short bf16x8;
typedef __attribute__((ext_vector_type(4))) float f32x4;

__device__ inline float b2f(u16 u) {
    union { unsigned int i; float f; } c; c.i = ((unsigned int)u) << 16; return c.f;
}
__device__ inline u16 f2b(float f) {
    union { float f; unsigned int i; } c; c.f = f;
    unsigned int i = c.i;
    i += 0x7fffu + ((i >> 16) & 1u);   // RTNE
    return (u16)(i >> 16);
}

// scalar generic storage
template <typename T> __device__ inline float ldH(const T* p, size_t i);
template <> __device__ inline float ldH<float>(const float* p, size_t i) { return p[i]; }
template <> __device__ inline float ldH<u16>(const u16* p, size_t i) { return b2f(p[i]); }
template <typename T> __device__ inline void stH(T* p, size_t i, float v);
template <> __device__ inline void stH<float>(float* p, size_t i, float v) { p[i] = v; }
template <> __device__ inline void stH<u16>(u16* p, size_t i, float v) { p[i] = f2b(v); }

// vector4 generic load
template <typename T> __device__ inline float4 ld4(const T* p, size_t i);
template <> __device__ inline float4 ld4<float>(const float* p, size_t i) { return *(const float4*)(p + i); }
template <> __device__ inline float4 ld4<u16>(const u16* p, size_t i) {
    ushort4 u = *(const ushort4*)(p + i);
    return make_float4(b2f(u.x), b2f(u.y), b2f(u.z), b2f(u.w));
}

__device__ inline float nlrelu(float z) { return (z > 0.f) ? -z : -0.01f * z; }  // -leaky_relu
__device__ inline float4 score4(float4 a, float4 b) {
    return make_float4(nlrelu(a.x + b.x), nlrelu(a.y + b.y), nlrelu(a.z + b.z), nlrelu(a.w + b.w));
}

// ---------------- weight frag-order split decomposition ----------------
__global__ void prep_w1frag(const float* __restrict__ Wh, u16* __restrict__ B1h, u16* __restrict__ B1l) {
    int i = blockIdx.x * 256 + threadIdx.x;          // 32768
    if (i >= 32768) return;
    int j = i & 7, lane = (i >> 3) & 63, kg = (i >> 9) & 3, nt = i >> 11;
    int n = nt * 16 + (lane & 15);
    int k = kg * 32 + ((lane >> 4) << 3) + j;
    float val = Wh[(n >> 6) * (128 * 64) + k * 64 + (n & 63)];
    u16 hi = f2b(val);
    B1h[i] = hi;
    B1l[i] = f2b(val - b2f(hi));
}
__global__ void prep_w2frag(const float* __restrict__ Wo, u16* __restrict__ B2h, u16* __restrict__ B2l) {
    int i = blockIdx.x * 256 + threadIdx.x;          // 16384
    if (i >= 16384) return;
    int j = i & 7, lane = (i >> 3) & 63, kg = (i >> 9) & 7, nt = i >> 12;
    int n = nt * 16 + (lane & 15);
    int k = kg * 32 + ((lane >> 4) << 3) + j;
    float val = Wo[k * 64 + n];
    u16 hi = f2b(val);
    B2h[i] = hi;
    B2l[i] = f2b(val - b2f(hi));
}

__global__ void zero2(int* __restrict__ a, int* __restrict__ b, int n) {
    int i = blockIdx.x * 256 + threadIdx.x;
    if (i < n) { a[i] = 0; b[i] = 0; }
}

// ---------------- CSR build ----------------
__global__ void count_edges(const int* __restrict__ src, int* __restrict__ counts, int E, int N) {
    int e = blockIdx.x * 256 + threadIdx.x;
    if (e >= E) return;
    int s = src[e];
    s = ((unsigned)s < (unsigned)N) ? s : 0;
    atomicAdd(&counts[s], 1);
}

__global__ __launch_bounds__(1024) void scan_p1(const int* __restrict__ counts, int* __restrict__ pre,
                                                int* __restrict__ bsum, int n) {
    const int t = threadIdx.x, lane = t & 63, w = t >> 6;
    __shared__ int wsum[16];
    int i = blockIdx.x * 1024 + t;
    int v = (i < n) ? counts[i] : 0;
    int orig = v;
    for (int d = 1; d < 64; d <<= 1) { int x = __shfl_up(v, d); if (lane >= d) v += x; }
    if (lane == 63) wsum[w] = v;
    __syncthreads();
    if (t == 0) {
        int acc = 0;
        for (int j = 0; j < 16; j++) { int tmp = wsum[j]; wsum[j] = acc; acc += tmp; }
        bsum[blockIdx.x] = acc;
    }
    __syncthreads();
    if (i < n) pre[i] = wsum[w] + (v - orig);
}
__global__ void scan_p2(int* __restrict__ bsum, int nb) {
    if (threadIdx.x == 0) {
        int acc = 0;
        for (int j = 0; j < nb; j++) { int tmp = bsum[j]; bsum[j] = acc; acc += tmp; }
        bsum[nb] = acc;
    }
}
__global__ void scan_p3(const int* __restrict__ pre, const int* __restrict__ bsum,
                        int* __restrict__ row_start, int n, int nb) {
    int i = blockIdx.x * 256 + threadIdx.x;
    if (i < n) row_start[i] = pre[i] + bsum[i >> 10];
    else if (i == n) row_start[n] = bsum[nb];
}

__global__ void scatter_edges(const int* __restrict__ src, const int* __restrict__ dst,
                              const int* __restrict__ row_start, int* __restrict__ cursor,
                              int* __restrict__ edge_dst, int E, int N) {
    int e = blockIdx.x * 256 + threadIdx.x;
    if (e >= E) return;
    int s = src[e];
    s = ((unsigned)s < (unsigned)N) ? s : 0;
    int d = dst[e];
    d = ((unsigned)d < (unsigned)N) ? d : 0;
    int pos = atomicAdd(&cursor[s], 1);
    int idx = row_start[s] + pos;
    if ((unsigned)idx < (unsigned)E) edge_dst[idx] = d;
}

// ---------------- GEMM1 (split-bf16 MFMA): H1[Mx256](bf16) = X[Mx128] @ W1^T, fused s1/s2 ----------------
template <typename HT1>
__global__ __launch_bounds__(256) void gemm1_mfma(const float* __restrict__ X,
        const u16* __restrict__ B1h, const u16* __restrict__ B1l,
        const float* __restrict__ attnH,
        HT1* __restrict__ H1, float* __restrict__ s1, float* __restrict__ s2, int M) {
    const int lane = threadIdx.x & 63, wave = threadIdx.x >> 6;
    const int row0 = (blockIdx.x * 4 + wave) * 16;
    if (row0 >= M) return;
    const int mrow = row0 + (lane & 15);
    const int koff = (lane >> 4) * 8;
    const float* aptr = X + (size_t)mrow * 128 + koff;

    f32x4 acc[16];
#pragma unroll
    for (int c = 0; c < 16; c++) acc[c] = (f32x4){0.f, 0.f, 0.f, 0.f};

#pragma unroll
    for (int kg = 0; kg < 4; kg++) {
        float av[8];
        *(float4*)av       = *(const float4*)(aptr + kg * 32);
        *(float4*)(av + 4) = *(const float4*)(aptr + kg * 32 + 4);
        bf16x8 ah, al;
#pragma unroll
        for (int j = 0; j < 8; j++) {
            u16 h = f2b(av[j]);
            ah[j] = (short)h;
            al[j] = (short)f2b(av[j] - b2f(h));
        }
#pragma unroll
        for (int nt = 0; nt < 16; nt++) {
            const size_t bidx = (size_t)(((nt << 2) + kg) * 64 + lane) * 8;
            bf16x8 bh = *(const bf16x8*)(B1h + bidx);
            bf16x8 bl = *(const bf16x8*)(B1l + bidx);
            acc[nt] = __builtin_amdgcn_mfma_f32_16x16x32_bf16(ah, bh, acc[nt], 0, 0, 0);
            acc[nt] = __builtin_amdgcn_mfma_f32_16x16x32_bf16(al, bh, acc[nt], 0, 0, 0);
            acc[nt] = __builtin_amdgcn_mfma_f32_16x16x32_bf16(ah, bl, acc[nt], 0, 0, 0);
        }
    }
    const int rbase = (lane >> 4) * 4;
    const int colq = lane & 15;
#pragma unroll
    for (int h = 0; h < 4; h++) {
        float s1a[4] = {0.f, 0.f, 0.f, 0.f}, s2a[4] = {0.f, 0.f, 0.f, 0.f};
#pragma unroll
        for (int q = 0; q < 4; q++) {
            const int nt = h * 4 + q;
            const int col = nt * 16 + colq;
            const float a1v = attnH[h * 128 + (col & 63)];
            const float a2v = attnH[h * 128 + 64 + (col & 63)];
#pragma unroll
            for (int r = 0; r < 4; r++) {
                float c = acc[nt][r];
                stH(H1, (size_t)(row0 + rbase + r) * 256 + col, c);
                s1a[r] += c * a1v;
                s2a[r] += c * a2v;
            }
        }
#pragma unroll
        for (int off = 1; off < 16; off <<= 1)
#pragma unroll
            for (int r = 0; r < 4; r++) {
                s1a[r] += __shfl_xor(s1a[r], off);
                s2a[r] += __shfl_xor(s2a[r], off);
            }
        if (colq == 0)
#pragma unroll
            for (int r = 0; r < 4; r++) {
                s1[(size_t)(row0 + rbase + r) * 4 + h] = s1a[r];
                s2[(size_t)(row0 + rbase + r) * 4 + h] = s2a[r];
            }
    }
}

// ---------------- GEMM2 (split-bf16 MFMA): H2[Mx64](bf16) = Hc @ W2^T, fused s1b/s2b ----------------
template <bool HCL, typename HT2>
__global__ __launch_bounds__(256) void gemm2_mfma(const u16* __restrict__ Ahp, const u16* __restrict__ Alp,
        const u16* __restrict__ B2h, const u16* __restrict__ B2l,
        const float* __restrict__ attnO,
        HT2* __restrict__ H2, float* __restrict__ s1b, float* __restrict__ s2b, int M) {
    const int lane = threadIdx.x & 63, wave = threadIdx.x >> 6;
    const int row0 = (blockIdx.x * 4 + wave) * 16;
    if (row0 >= M) return;
    const int mrow = row0 + (lane & 15);
    const int koff = (lane >> 4) * 8;
    const u16* ah_p = Ahp + (size_t)mrow * 256 + koff;
    const u16* al_p = Alp + (size_t)mrow * 256 + koff;

    f32x4 acc[4];
#pragma unroll
    for (int c = 0; c < 4; c++) acc[c] = (f32x4){0.f, 0.f, 0.f, 0.f};

#pragma unroll
    for (int kg = 0; kg < 8; kg++) {
        bf16x8 ah = *(const bf16x8*)(ah_p + kg * 32);
        bf16x8 al;
        if (HCL) al = *(const bf16x8*)(al_p + kg * 32);
#pragma unroll
        for (int nt = 0; nt < 4; nt++) {
            const size_t bidx = (size_t)(((nt << 3) + kg) * 64 + lane) * 8;
            bf16x8 bh = *(const bf16x8*)(B2h + bidx);
            bf16x8 bl = *(const bf16x8*)(B2l + bidx);
            acc[nt] = __builtin_amdgcn_mfma_f32_16x16x32_bf16(ah, bh, acc[nt], 0, 0, 0);
            if (HCL) acc[nt] = __builtin_amdgcn_mfma_f32_16x16x32_bf16(al, bh, acc[nt], 0, 0, 0);
            acc[nt] = __builtin_amdgcn_mfma_f32_16x16x32_bf16(ah, bl, acc[nt], 0, 0, 0);
        }
    }
    const int rbase = (lane >> 4) * 4;
    const int colq = lane & 15;
    float s1a[4] = {0.f, 0.f, 0.f, 0.f}, s2a[4] = {0.f, 0.f, 0.f, 0.f};
#pragma unroll
    for (int nt = 0; nt < 4; nt++) {
        const int col = nt * 16 + colq;
        const float a1v = attnO[col];
        const float a2v = attnO[64 + col];
#pragma unroll
        for (int r = 0; r < 4; r++) {
            float c = acc[nt][r];
            stH(H2, (size_t)(row0 + rbase + r) * 64 + col, c);
            s1a[r] += c * a1v;
            s2a[r] += c * a2v;
        }
    }
#pragma unroll
    for (int off = 1; off < 16; off <<= 1)
#pragma unroll
        for (int r = 0; r < 4; r++) {
            s1a[r] += __shfl_xor(s1a[r], off);
            s2a[r] += __shfl_xor(s2a[r], off);
        }
    if (colq == 0)
#pragma unroll
        for (int r = 0; r < 4; r++) {
            s1b[row0 + rbase + r] = s1a[r];
            s2b[row0 + rbase + r] = s2a[r];
        }
}

// ---------------- layer-1 aggregate: one wave per node; H gathered bf16; hcat hi(/lo) out ----------------
template <typename HT, bool WL>
__global__ __launch_bounds__(256) void agg_l1(const int* __restrict__ rowst, const int* __restrict__ edged,
                                              const float* __restrict__ s1, const float* __restrict__ s2,
                                              const HT* __restrict__ H,
                                              u16* __restrict__ hcat_h, u16* __restrict__ hcat_l,
                                              int N, int E) {
    __shared__ float wls[4][256];
    __shared__ int dls[4][64];
    const int t = threadIdx.x, lane = t & 63, wave = t >> 6;
    const int node = blockIdx.x * 4 + wave;
    if (node >= N) return;
    int beg = rowst[node], end = rowst[node + 1];
    beg = max(0, min(beg, E)); end = max(beg, min(end, E));
    const int deg = end - beg;
    const int head = lane >> 4;
    const size_t obase = (size_t)node * 256 + lane * 4;
    if (deg == 0) {
        ushort4 z = {0, 0, 0, 0};
        *(ushort4*)(hcat_h + obase) = z;
        if (WL) *(ushort4*)(hcat_l + obase) = z;
        return;
    }
    const float4 s1v = *(const float4*)(s1 + (size_t)node * 4);

    float4 acc = make_float4(0.f, 0.f, 0.f, 0.f);
    if (deg <= 64) {
        int d = 0;
        if (lane < deg) { d = edged[beg + lane]; d = ((unsigned)d < (unsigned)N) ? d : 0; }
        dls[wave][lane] = d;
        float4 s2v = *(const float4*)(s2 + (size_t)d * 4);
        float4 sc = score4(s1v, s2v);
        if (lane >= deg) sc = make_float4(-3e38f, -3e38f, -3e38f, -3e38f);
        float4 m = sc;
#pragma unroll
        for (int off = 32; off > 0; off >>= 1) {
            m.x = fmaxf(m.x, __shfl_xor(m.x, off));
            m.y = fmaxf(m.y, __shfl_xor(m.y, off));
            m.z = fmaxf(m.z, __shfl_xor(m.z, off));
            m.w = fmaxf(m.w, __shfl_xor(m.w, off));
        }
        float4 ex = make_float4(0.f, 0.f, 0.f, 0.f);
        if (lane < deg) ex = make_float4(__expf(sc.x - m.x), __expf(sc.y - m.y),
                                         __expf(sc.z - m.z), __expf(sc.w - m.w));
        float4 sm = ex;
#pragma unroll
        for (int off = 32; off > 0; off >>= 1) {
            sm.x += __shfl_xor(sm.x, off);
            sm.y += __shfl_xor(sm.y, off);
            sm.z += __shfl_xor(sm.z, off);
            sm.w += __shfl_xor(sm.w, off);
        }
        float4 w4 = make_float4(ex.x / sm.x, ex.y / sm.y, ex.z / sm.z, ex.w / sm.w);
        *(float4*)&wls[wave][lane * 4] = w4;
        // unroll-by-4 gather: 4 independent row loads in flight
        int e = 0;
        for (; e + 4 <= deg; e += 4) {
            int d0 = dls[wave][e], d1 = dls[wave][e + 1], d2 = dls[wave][e + 2], d3 = dls[wave][e + 3];
            float4 h0 = ld4(H, (size_t)d0 * 256 + lane * 4);
            float4 h1 = ld4(H, (size_t)d1 * 256 + lane * 4);
            float4 h2 = ld4(H, (size_t)d2 * 256 + lane * 4);
            float4 h3 = ld4(H, (size_t)d3 * 256 + lane * 4);
            float w0 = wls[wave][(e    ) * 4 + head];
            float w1 = wls[wave][(e + 1) * 4 + head];
            float w2 = wls[wave][(e + 2) * 4 + head];
            float w3 = wls[wave][(e + 3) * 4 + head];
            acc.x += w0 * h0.x + w1 * h1.x + w2 * h2.x + w3 * h3.x;
            acc.y += w0 * h0.y + w1 * h1.y + w2 * h2.y + w3 * h3.y;
            acc.z += w0 * h0.z + w1 * h1.z + w2 * h2.z + w3 * h3.z;
            acc.w += w0 * h0.w + w1 * h1.w + w2 * h2.w + w3 * h3.w;
        }
        for (; e < deg; e++) {
            float w = wls[wave][e * 4 + head];
            float4 h4 = ld4(H, (size_t)dls[wave][e] * 256 + lane * 4);
            acc.x += w * h4.x; acc.y += w * h4.y; acc.z += w * h4.z; acc.w += w * h4.w;
        }
    } else {
        float4 m = make_float4(-3e38f, -3e38f, -3e38f, -3e38f);
        for (int e = beg + lane; e < end; e += 64) {
            int d = edged[e]; d = ((unsigned)d < (unsigned)N) ? d : 0;
            float4 sc = score4(s1v, *(const float4*)(s2 + (size_t)d * 4));
            m.x = fmaxf(m.x, sc.x); m.y = fmaxf(m.y, sc.y); m.z = fmaxf(m.z, sc.z); m.w = fmaxf(m.w, sc.w);
        }
#pragma unroll
        for (int off = 32; off > 0; off >>= 1) {
            m.x = fmaxf(m.x, __shfl_xor(m.x, off));
            m.y = fmaxf(m.y, __shfl_xor(m.y, off));
            m.z = fmaxf(m.z, __shfl_xor(m.z, off));
            m.w = fmaxf(m.w, __shfl_xor(m.w, off));
        }
        float4 sm = make_float4(0.f, 0.f, 0.f, 0.f);
        for (int e = beg + lane; e < end; e += 64) {
            int d = edged[e]; d = ((unsigned)d < (unsigned)N) ? d : 0;
            float4 sc = score4(s1v, *(const float4*)(s2 + (size_t)d * 4));
            sm.x += __expf(sc.x - m.x); sm.y += __expf(sc.y - m.y);
            sm.z += __expf(sc.z - m.z); sm.w += __expf(sc.w - m.w);
        }
#pragma unroll
        for (int off = 32; off > 0; off >>= 1) {
            sm.x += __shfl_xor(sm.x, off);
            sm.y += __shfl_xor(sm.y, off);
            sm.z += __shfl_xor(sm.z, off);
            sm.w += __shfl_xor(sm.w, off);
        }
        float4 inv = make_float4(1.f / sm.x, 1.f / sm.y, 1.f / sm.z, 1.f / sm.w);
        for (int e = beg; e < end; e++) {
            int dd = edged[e]; dd = ((unsigned)dd < (unsigned)N) ? dd : 0;
            float4 sc = score4(s1v, *(const float4*)(s2 + (size_t)dd * 4));
            float wv[4] = { __expf(sc.x - m.x) * inv.x, __expf(sc.y - m.y) * inv.y,
                            __expf(sc.z - m.z) * inv.z, __expf(sc.w - m.w) * inv.w };
            float w = (head == 0) ? wv[0] : (head == 1) ? wv[1] : (head == 2) ? wv[2] : wv[3];
            float4 h4 = ld4(H, (size_t)dd * 256 + lane * 4);
            acc.x += w * h4.x; acc.y += w * h4.y; acc.z += w * h4.z; acc.w += w * h4.w;
        }
    }
    acc.x = (acc.x > 0.f) ? acc.x : (__expf(acc.x) - 1.f);
    acc.y = (acc.y > 0.f) ? acc.y : (__expf(acc.y) - 1.f);
    acc.z = (acc.z > 0.f) ? acc.z : (__expf(acc.z) - 1.f);
    acc.w = (acc.w > 0.f) ? acc.w : (__expf(acc.w) - 1.f);
    ushort4 hv, lv;
    hv.x = f2b(acc.x); hv.y = f2b(acc.y); hv.z = f2b(acc.z); hv.w = f2b(acc.w);
    *(ushort4*)(hcat_h + obase) = hv;
    if (WL) {
        lv.x = f2b(acc.x - b2f(hv.x)); lv.y = f2b(acc.y - b2f(hv.y));
        lv.z = f2b(acc.z - b2f(hv.z)); lv.w = f2b(acc.w - b2f(hv.w));
        *(ushort4*)(hcat_l + obase) = lv;
    }
}

// ---------------- layer-2 aggregate: one wave per node, 64 features; H bf16 ----------------
template <typename HT>
__global__ __launch_bounds__(256) void agg_l2(const int* __restrict__ rowst, const int* __restrict__ edged,
                                              const float* __restrict__ s1, const float* __restrict__ s2,
                                              const HT* __restrict__ H, float* __restrict__ outp, int N, int E) {
    __shared__ float wls[4][64];
    __shared__ int dls[4][64];
    const int t = threadIdx.x, lane = t & 63, wave = t >> 6;
    const int node = blockIdx.x * 4 + wave;
    if (node >= N) return;
    int beg = rowst[node], end = rowst[node + 1];
    beg = max(0, min(beg, E)); end = max(beg, min(end, E));
    const int deg = end - beg;
    if (deg == 0) { outp[(size_t)node * 64 + lane] = 0.f; return; }
    const float s1v = s1[node];

    float acc = 0.f;
    if (deg <= 64) {
        int d = 0;
        if (lane < deg) { d = edged[beg + lane]; d = ((unsigned)d < (unsigned)N) ? d : 0; }
        dls[wave][lane] = d;
        float z = s1v + s2[d];
        float sc = (lane < deg) ? nlrelu(z) : -3e38f;
        float m = sc;
#pragma unroll
        for (int off = 32; off > 0; off >>= 1) m = fmaxf(m, __shfl_xor(m, off));
        float ex = (lane < deg) ? __expf(sc - m) : 0.f;
        float sm = ex;
#pragma unroll
        for (int off = 32; off > 0; off >>= 1) sm += __shfl_xor(sm, off);
        wls[wave][lane] = ex / sm;
        int e = 0;
        for (; e + 4 <= deg; e += 4) {
            int d0 = dls[wave][e], d1 = dls[wave][e + 1], d2 = dls[wave][e + 2], d3 = dls[wave][e + 3];
            float h0 = ldH(H, (size_t)d0 * 64 + lane);
            float h1 = ldH(H, (size_t)d1 * 64 + lane);
            float h2 = ldH(H, (size_t)d2 * 64 + lane);
            float h3 = ldH(H, (size_t)d3 * 64 + lane);
            acc += wls[wave][e] * h0 + wls[wave][e + 1] * h1 + wls[wave][e + 2] * h2 + wls[wave][e + 3] * h3;
        }
        for (; e < deg; e++)
            acc += wls[wave][e] * ldH(H, (size_t)dls[wave][e] * 64 + lane);
    } else {
        float m = -3e38f;
        for (int e = beg + lane; e < end; e += 64) {
            int d = edged[e]; d = ((unsigned)d < (unsigned)N) ? d : 0;
            m = fmaxf(m, nlrelu(s1v + s2[d]));
        }
#pragma unroll
        for (int off = 32; off > 0; off >>= 1) m = fmaxf(m, __shfl_xor(m, off));
        float sm = 0.f;
        for (int e = beg + lane; e < end; e += 64) {
            int d = edged[e]; d = ((unsigned)d < (unsigned)N) ? d : 0;
            sm += __expf(nlrelu(s1v + s2[d]) - m);
        }
#pragma unroll
        for (int off = 32; off > 0; off >>= 1) sm += __shfl_xor(sm, off);
        float inv = 1.f / sm;
        for (int e = beg; e < end; e++) {
            int dd = edged[e]; dd = ((unsigned)dd < (unsigned)N) ? dd : 0;
            float w = __expf(nlrelu(s1v + s2[dd]) - m) * inv;
            acc += w * ldH(H, (size_t)dd * 64 + lane);
        }
    }
    outp[(size_t)node * 64 + lane] = acc;
}

// ---------------- host pipeline ----------------
template <bool WL>
static void run_pipeline(const float* x, const int* srcp, const int* dstp,
                         const float* Wh, const float* attnH, const float* Wo, const float* attnO,
                         float* out, char* base, int N, int E, hipStream_t stream) {
    size_t off = 0;
    auto take = [&](size_t b) { void* p = base + off; off += (b + 255) & ~(size_t)255; return p; };
    u16*   B1h    = (u16*)  take(32768 * 2);
    u16*   B1l    = (u16*)  take(32768 * 2);
    u16*   B2h    = (u16*)  take(16384 * 2);
    u16*   B2l    = (u16*)  take(16384 * 2);
    int*   counts = (int*)  take((size_t)N * 4);
    int*   cursor = (int*)  take((size_t)N * 4);
    int*   rowst  = (int*)  take((size_t)(N + 1) * 4);
    int*   edged  = (int*)  take((size_t)E * 4);
    int*   pre    = (int*)  take((size_t)N * 4);
    int*   bsum   = (int*)  take(4096);
    float* s1     = (float*)take((size_t)N * 4 * 4);
    float* s2     = (float*)take((size_t)N * 4 * 4);
    float* s1b    = (float*)take((size_t)N * 4);
    float* s2b    = (float*)take((size_t)N * 4);
    u16*   H1     = (u16*)  take((size_t)N * 256 * 2);   // bf16 — gather traffic halved
    u16*   hcat_h = (u16*)  take((size_t)N * 256 * 2);
    u16*   hcat_l = WL ? (u16*)take((size_t)N * 256 * 2) : hcat_h;
    u16*   H2     = (u16*)  take((size_t)N * 64 * 2);    // bf16

    prep_w1frag<<<128, 256, 0, stream>>>(Wh, B1h, B1l);
    prep_w2frag<<<64, 256, 0, stream>>>(Wo, B2h, B2l);
    zero2<<<(N + 255) / 256, 256, 0, stream>>>(counts, cursor, N);

    count_edges<<<(E + 255) / 256, 256, 0, stream>>>(srcp, counts, E, N);
    const int nb = (N + 1023) / 1024;
    scan_p1<<<nb, 1024, 0, stream>>>(counts, pre, bsum, N);
    scan_p2<<<1, 64, 0, stream>>>(bsum, nb);
    scan_p3<<<(N + 256) / 256, 256, 0, stream>>>(pre, bsum, rowst, N, nb);
    scatter_edges<<<(E + 255) / 256, 256, 0, stream>>>(srcp, dstp, rowst, cursor, edged, E, N);

    const int gemmGrid = ((N + 15) / 16 + 3) / 4;
    gemm1_mfma<<<gemmGrid, 256, 0, stream>>>(x, B1h, B1l, attnH, H1, s1, s2, N);
    agg_l1<u16, WL><<<(N + 3) / 4, 256, 0, stream>>>(rowst, edged, s1, s2, H1, hcat_h, hcat_l, N, E);

    gemm2_mfma<WL, u16><<<gemmGrid, 256, 0, stream>>>(hcat_h, hcat_l, B2h, B2l, attnO, H2, s1b, s2b, N);
    agg_l2<<<(N + 3) / 4, 256, 0, stream>>>(rowst, edged, s1b, s2b, H2, out, N, E);
}

extern "C" void kernel_launch(void* const* d_in, const int* in_sizes, int n_in,
                              void* d_out, int out_size, void* d_ws, size_t ws_size,
                              hipStream_t stream) {
    const float* x     = (const float*)d_in[0];
    const int*   ei    = (const int*)d_in[1];     // [2][E] int32
    const float* Wh    = (const float*)d_in[2];
    const float* attnH = (const float*)d_in[3];
    const float* Wo    = (const float*)d_in[4];
    const float* attnO = (const float*)d_in[5];
    float* out         = (float*)d_out;

    const int N = in_sizes[0] / 128;    // 50000
    const int E = in_sizes[1] / 2;      // 800000
    const int* srcp = ei;
    const int* dstp = ei + E;

    auto al = [](size_t b) { return (b + 255) & ~(size_t)255; };
    size_t misc = 2 * al(32768 * 2) + 2 * al(16384 * 2) +
                  3 * al((size_t)N * 4) + al((size_t)(N + 1) * 4) + al((size_t)E * 4) + al(4096) +
                  2 * al((size_t)N * 16) + 2 * al((size_t)N * 4);
    size_t h256b = al((size_t)N * 256 * 2);
    size_t h64b = al((size_t)N * 64 * 2);

    char* ws = (char*)d_ws;
    if (ws_size >= misc + 3 * h256b + h64b)       // plan X2: H1 bf16, hcat hi+lo, H2 bf16 (~91 MB)
        run_pipeline<true>(x, srcp, dstp, Wh, attnH, Wo, attnO, out, ws, N, E, stream);
    else                                          // plan Y2: drop hcat lo (~66 MB)
        run_pipeline<false>(x, srcp, dstp, Wh, attnH, Wo, attnO, out, ws, N, E, stream);
}

// Round 7
// 276.626 us; speedup vs baseline: 2.9650x; 1.1466x over previous
//
#include <hip/hip_runtime.h>

typedef unsigned short u16;
typedef _Float16 f16;
typedef __attribute__((ext_vector_type(8))) _Float16 f16x8;
typedef __attribute__((ext_vector_type(2))) _Float16 f16x2;
typedef __attribute__((ext_vector_type(4))) float f32x4;

__device__ inline float nlrelu(float z) { return (z > 0.f) ? -z : -0.01f * z; }  // -leaky_relu
__device__ inline float4 score4(float4 a, float4 b) {
    return make_float4(nlrelu(a.x + b.x), nlrelu(a.y + b.y), nlrelu(a.z + b.z), nlrelu(a.w + b.w));
}
__device__ inline unsigned packdup(float w) {
    f16x2 p = (f16x2){(f16)w, (f16)w};
    return __builtin_bit_cast(unsigned, p);
}

// ---------------- K1: weight frags (fp16) + zero counts/cursor ----------------
__global__ void k_init(const float* __restrict__ Wh, const float* __restrict__ Wo,
                       f16* __restrict__ B1, f16* __restrict__ B2,
                       int* __restrict__ counts, int* __restrict__ cursor, int N) {
    const int b = blockIdx.x;
    if (b < 128) {                       // W1 frag: 32768 elems
        int i = b * 256 + threadIdx.x;
        int j = i & 7, lane = (i >> 3) & 63, kg = (i >> 9) & 3, nt = i >> 11;
        int n = nt * 16 + (lane & 15);
        int k = kg * 32 + ((lane >> 4) << 3) + j;
        B1[i] = (f16)Wh[(n >> 6) * (128 * 64) + k * 64 + (n & 63)];
    } else if (b < 192) {                // W2 frag: 16384 elems
        int i = (b - 128) * 256 + threadIdx.x;
        int j = i & 7, lane = (i >> 3) & 63, kg = (i >> 9) & 7, nt = i >> 12;
        int n = nt * 16 + (lane & 15);
        int k = kg * 32 + ((lane >> 4) << 3) + j;
        B2[i] = (f16)Wo[k * 64 + n];
    } else {
        int i = (b - 192) * 256 + threadIdx.x;
        if (i < N) { counts[i] = 0; cursor[i] = 0; }
    }
}

// ---------------- CSR build ----------------
__global__ void count_edges(const int* __restrict__ src, int* __restrict__ counts, int E, int N) {
    int e = blockIdx.x * 256 + threadIdx.x;
    if (e >= E) return;
    int s = src[e];
    s = ((unsigned)s < (unsigned)N) ? s : 0;
    atomicAdd(&counts[s], 1);
}

__global__ __launch_bounds__(1024) void scan_p1(const int* __restrict__ counts, int* __restrict__ rowst,
                                                int* __restrict__ bsum, int n) {
    const int t = threadIdx.x, lane = t & 63, w = t >> 6;
    __shared__ int wsum[16];
    int i = blockIdx.x * 1024 + t;
    int v = (i < n) ? counts[i] : 0;
    int orig = v;
    for (int d = 1; d < 64; d <<= 1) { int x = __shfl_up(v, d); if (lane >= d) v += x; }
    if (lane == 63) wsum[w] = v;
    __syncthreads();
    if (t == 0) {
        int acc = 0;
        for (int j = 0; j < 16; j++) { int tmp = wsum[j]; wsum[j] = acc; acc += tmp; }
        bsum[blockIdx.x] = acc;
    }
    __syncthreads();
    if (i < n) rowst[i] = wsum[w] + (v - orig);   // local (per-1024-group) exclusive prefix
}

// p3 with inlined block-sum scan (nb <= 64, serial per block is cheap)
__global__ void scan_p3(const int* __restrict__ bsum, int* __restrict__ rowst, int n, int nb) {
    __shared__ int sh_pre, sh_tot;
    const int i = blockIdx.x * 256 + threadIdx.x;
    const int g = (blockIdx.x * 256) >> 10;      // whole block shares one 1024-group
    if (threadIdx.x == 0) {
        int acc = 0, pre = 0;
        for (int j = 0; j < nb; j++) { if (j == g) pre = acc; acc += bsum[j]; }
        if (g >= nb) pre = acc;
        sh_pre = pre; sh_tot = acc;
    }
    __syncthreads();
    if (i < n) rowst[i] += sh_pre;
    else if (i == n) rowst[n] = sh_tot;
}

// ---------------- K5: scatter_edges + gemm1 (f16 MFMA, fused s1/s2), blockIdx-partitioned ----------------
__global__ __launch_bounds__(256) void k_scatter_gemm1(
        const int* __restrict__ src, const int* __restrict__ dst,
        const int* __restrict__ rowst, int* __restrict__ cursor, int* __restrict__ edged,
        const float* __restrict__ X, const f16* __restrict__ B1, const float* __restrict__ attnH,
        f16* __restrict__ H1, float* __restrict__ s1, float* __restrict__ s2,
        int M, int E, int N, int Gg) {
    if ((int)blockIdx.x >= Gg) {
        // ---- scatter path ----
        int e = (blockIdx.x - Gg) * 256 + threadIdx.x;
        if (e >= E) return;
        int s = src[e];
        s = ((unsigned)s < (unsigned)N) ? s : 0;
        int d = dst[e];
        d = ((unsigned)d < (unsigned)N) ? d : 0;
        int pos = atomicAdd(&cursor[s], 1);
        edged[rowst[s] + pos] = d;
        return;
    }
    // ---- gemm1 path ----
    const int lane = threadIdx.x & 63, wave = threadIdx.x >> 6;
    const int row0 = (blockIdx.x * 4 + wave) * 16;
    if (row0 >= M) return;
    const int mrow = row0 + (lane & 15);
    const int koff = (lane >> 4) * 8;
    const float* aptr = X + (size_t)mrow * 128 + koff;

    f32x4 acc[16];
#pragma unroll
    for (int c = 0; c < 16; c++) acc[c] = (f32x4){0.f, 0.f, 0.f, 0.f};

#pragma unroll
    for (int kg = 0; kg < 4; kg++) {
        float av[8];
        *(float4*)av       = *(const float4*)(aptr + kg * 32);
        *(float4*)(av + 4) = *(const float4*)(aptr + kg * 32 + 4);
        f16x8 a;
#pragma unroll
        for (int j = 0; j < 8; j++) a[j] = (f16)av[j];
#pragma unroll
        for (int nt = 0; nt < 16; nt++) {
            const size_t bidx = (size_t)(((nt << 2) + kg) * 64 + lane) * 8;
            f16x8 bfr = *(const f16x8*)(B1 + bidx);
            acc[nt] = __builtin_amdgcn_mfma_f32_16x16x32_f16(a, bfr, acc[nt], 0, 0, 0);
        }
    }
    const int rbase = (lane >> 4) * 4;
    const int colq = lane & 15;
#pragma unroll
    for (int h = 0; h < 4; h++) {
        float s1a[4] = {0.f, 0.f, 0.f, 0.f}, s2a[4] = {0.f, 0.f, 0.f, 0.f};
#pragma unroll
        for (int q = 0; q < 4; q++) {
            const int nt = h * 4 + q;
            const int col = nt * 16 + colq;
            const float a1v = attnH[h * 128 + (col & 63)];
            const float a2v = attnH[h * 128 + 64 + (col & 63)];
#pragma unroll
            for (int r = 0; r < 4; r++) {
                float c = acc[nt][r];
                H1[(size_t)(row0 + rbase + r) * 256 + col] = (f16)c;
                s1a[r] += c * a1v;
                s2a[r] += c * a2v;
            }
        }
#pragma unroll
        for (int off = 1; off < 16; off <<= 1)
#pragma unroll
            for (int r = 0; r < 4; r++) {
                s1a[r] += __shfl_xor(s1a[r], off);
                s2a[r] += __shfl_xor(s2a[r], off);
            }
        if (colq == 0)
#pragma unroll
            for (int r = 0; r < 4; r++) {
                s1[(size_t)(row0 + rbase + r) * 4 + h] = s1a[r];
                s2[(size_t)(row0 + rbase + r) * 4 + h] = s2a[r];
            }
    }
}

// ---------------- gemm2 (f16 MFMA): H2[Mx64] = hcat[Mx256] @ W2^T, fused s1b/s2b ----------------
__global__ __launch_bounds__(256) void gemm2_f16(const f16* __restrict__ Hc, const f16* __restrict__ B2,
        const float* __restrict__ attnO,
        f16* __restrict__ H2, float* __restrict__ s1b, float* __restrict__ s2b, int M) {
    const int lane = threadIdx.x & 63, wave = threadIdx.x >> 6;
    const int row0 = (blockIdx.x * 4 + wave) * 16;
    if (row0 >= M) return;
    const int mrow = row0 + (lane & 15);
    const int koff = (lane >> 4) * 8;
    const f16* ap = Hc + (size_t)mrow * 256 + koff;

    f32x4 acc[4];
#pragma unroll
    for (int c = 0; c < 4; c++) acc[c] = (f32x4){0.f, 0.f, 0.f, 0.f};

#pragma unroll
    for (int kg = 0; kg < 8; kg++) {
        f16x8 a = *(const f16x8*)(ap + kg * 32);
#pragma unroll
        for (int nt = 0; nt < 4; nt++) {
            const size_t bidx = (size_t)(((nt << 3) + kg) * 64 + lane) * 8;
            f16x8 bfr = *(const f16x8*)(B2 + bidx);
            acc[nt] = __builtin_amdgcn_mfma_f32_16x16x32_f16(a, bfr, acc[nt], 0, 0, 0);
        }
    }
    const int rbase = (lane >> 4) * 4;
    const int colq = lane & 15;
    float s1a[4] = {0.f, 0.f, 0.f, 0.f}, s2a[4] = {0.f, 0.f, 0.f, 0.f};
#pragma unroll
    for (int nt = 0; nt < 4; nt++) {
        const int col = nt * 16 + colq;
        const float a1v = attnO[col];
        const float a2v = attnO[64 + col];
#pragma unroll
        for (int r = 0; r < 4; r++) {
            float c = acc[nt][r];
            H2[(size_t)(row0 + rbase + r) * 64 + col] = (f16)c;
            s1a[r] += c * a1v;
            s2a[r] += c * a2v;
        }
    }
#pragma unroll
    for (int off = 1; off < 16; off <<= 1)
#pragma unroll
        for (int r = 0; r < 4; r++) {
            s1a[r] += __shfl_xor(s1a[r], off);
            s2a[r] += __shfl_xor(s2a[r], off);
        }
    if (colq == 0)
#pragma unroll
        for (int r = 0; r < 4; r++) {
            s1b[row0 + rbase + r] = s1a[r];
            s2b[row0 + rbase + r] = s2a[r];
        }
}

// ---------------- layer-1 aggregate: one wave per node, pk_fma_f16 gather ----------------
__global__ __launch_bounds__(256) void agg_l1(const int* __restrict__ rowst, const int* __restrict__ edged,
                                              const float* __restrict__ s1, const float* __restrict__ s2,
                                              const f16* __restrict__ H, f16* __restrict__ hcat, int N) {
    __shared__ unsigned wls[4][64][4];     // packed (w,w) half2 per edge per head
    __shared__ int dls[4][64];
    const int t = threadIdx.x, lane = t & 63, wave = t >> 6;
    const int node = blockIdx.x * 4 + wave;
    if (node >= N) return;
    const int beg = rowst[node], end = rowst[node + 1];
    const int deg = end - beg;
    const int head = lane >> 4;
    f16* outp = hcat + (size_t)node * 256 + lane * 4;
    if (deg == 0) { *(uint2*)outp = make_uint2(0u, 0u); return; }
    const float4 s1v = *(const float4*)(s1 + (size_t)node * 4);

    float r0, r1, r2, r3;
    if (deg <= 64) {
        int d = 0;
        if (lane < deg) d = edged[beg + lane];
        dls[wave][lane] = d;
        float4 s2v = *(const float4*)(s2 + (size_t)d * 4);
        float4 sc = score4(s1v, s2v);
        if (lane >= deg) sc = make_float4(-3e38f, -3e38f, -3e38f, -3e38f);
        float4 m = sc;
#pragma unroll
        for (int off = 32; off > 0; off >>= 1) {
            m.x = fmaxf(m.x, __shfl_xor(m.x, off));
            m.y = fmaxf(m.y, __shfl_xor(m.y, off));
            m.z = fmaxf(m.z, __shfl_xor(m.z, off));
            m.w = fmaxf(m.w, __shfl_xor(m.w, off));
        }
        float4 ex = make_float4(0.f, 0.f, 0.f, 0.f);
        if (lane < deg) ex = make_float4(__expf(sc.x - m.x), __expf(sc.y - m.y),
                                         __expf(sc.z - m.z), __expf(sc.w - m.w));
        float4 sm = ex;
#pragma unroll
        for (int off = 32; off > 0; off >>= 1) {
            sm.x += __shfl_xor(sm.x, off);
            sm.y += __shfl_xor(sm.y, off);
            sm.z += __shfl_xor(sm.z, off);
            sm.w += __shfl_xor(sm.w, off);
        }
        wls[wave][lane][0] = packdup(ex.x / sm.x);
        wls[wave][lane][1] = packdup(ex.y / sm.y);
        wls[wave][lane][2] = packdup(ex.z / sm.z);
        wls[wave][lane][3] = packdup(ex.w / sm.w);
        // phase B: 4 independent fp16 accumulator sets (bounded rounding chains)
        f16x2 a01[4], a23[4];
#pragma unroll
        for (int j = 0; j < 4; j++) { a01[j] = (f16x2)(f16)0.f; a23[j] = (f16x2)(f16)0.f; }
        int e = 0;
        for (; e + 4 <= deg; e += 4) {
#pragma unroll
            for (int j = 0; j < 4; j++) {
                int dd = dls[wave][e + j];
                uint2 raw = *(const uint2*)(H + (size_t)dd * 256 + lane * 4);
                f16x2 lo = __builtin_bit_cast(f16x2, raw.x);
                f16x2 hi = __builtin_bit_cast(f16x2, raw.y);
                f16x2 w2 = __builtin_bit_cast(f16x2, wls[wave][e + j][head]);
                a01[j] += w2 * lo;
                a23[j] += w2 * hi;
            }
        }
        for (; e < deg; e++) {
            int dd = dls[wave][e];
            uint2 raw = *(const uint2*)(H + (size_t)dd * 256 + lane * 4);
            f16x2 lo = __builtin_bit_cast(f16x2, raw.x);
            f16x2 hi = __builtin_bit_cast(f16x2, raw.y);
            f16x2 w2 = __builtin_bit_cast(f16x2, wls[wave][e][head]);
            a01[0] += w2 * lo;
            a23[0] += w2 * hi;
        }
        r0 = (float)a01[0][0] + (float)a01[1][0] + (float)a01[2][0] + (float)a01[3][0];
        r1 = (float)a01[0][1] + (float)a01[1][1] + (float)a01[2][1] + (float)a01[3][1];
        r2 = (float)a23[0][0] + (float)a23[1][0] + (float)a23[2][0] + (float)a23[3][0];
        r3 = (float)a23[0][1] + (float)a23[1][1] + (float)a23[2][1] + (float)a23[3][1];
    } else {
        // generic slow path (deg > 64), fp32 math
        float4 m = make_float4(-3e38f, -3e38f, -3e38f, -3e38f);
        for (int e = beg + lane; e < end; e += 64) {
            int d = edged[e];
            float4 sc = score4(s1v, *(const float4*)(s2 + (size_t)d * 4));
            m.x = fmaxf(m.x, sc.x); m.y = fmaxf(m.y, sc.y); m.z = fmaxf(m.z, sc.z); m.w = fmaxf(m.w, sc.w);
        }
#pragma unroll
        for (int off = 32; off > 0; off >>= 1) {
            m.x = fmaxf(m.x, __shfl_xor(m.x, off));
            m.y = fmaxf(m.y, __shfl_xor(m.y, off));
            m.z = fmaxf(m.z, __shfl_xor(m.z, off));
            m.w = fmaxf(m.w, __shfl_xor(m.w, off));
        }
        float4 sm = make_float4(0.f, 0.f, 0.f, 0.f);
        for (int e = beg + lane; e < end; e += 64) {
            int d = edged[e];
            float4 sc = score4(s1v, *(const float4*)(s2 + (size_t)d * 4));
            sm.x += __expf(sc.x - m.x); sm.y += __expf(sc.y - m.y);
            sm.z += __expf(sc.z - m.z); sm.w += __expf(sc.w - m.w);
        }
#pragma unroll
        for (int off = 32; off > 0; off >>= 1) {
            sm.x += __shfl_xor(sm.x, off);
            sm.y += __shfl_xor(sm.y, off);
            sm.z += __shfl_xor(sm.z, off);
            sm.w += __shfl_xor(sm.w, off);
        }
        float4 inv = make_float4(1.f / sm.x, 1.f / sm.y, 1.f / sm.z, 1.f / sm.w);
        float4 acc = make_float4(0.f, 0.f, 0.f, 0.f);
        for (int e = beg; e < end; e++) {
            int dd = edged[e];
            float4 sc = score4(s1v, *(const float4*)(s2 + (size_t)dd * 4));
            float wv[4] = { __expf(sc.x - m.x) * inv.x, __expf(sc.y - m.y) * inv.y,
                            __expf(sc.z - m.z) * inv.z, __expf(sc.w - m.w) * inv.w };
            float w = (head == 0) ? wv[0] : (head == 1) ? wv[1] : (head == 2) ? wv[2] : wv[3];
            const f16* hp = H + (size_t)dd * 256 + lane * 4;
            acc.x += w * (float)hp[0]; acc.y += w * (float)hp[1];
            acc.z += w * (float)hp[2]; acc.w += w * (float)hp[3];
        }
        r0 = acc.x; r1 = acc.y; r2 = acc.z; r3 = acc.w;
    }
    // ELU + fp16 store
    r0 = (r0 > 0.f) ? r0 : (__expf(r0) - 1.f);
    r1 = (r1 > 0.f) ? r1 : (__expf(r1) - 1.f);
    r2 = (r2 > 0.f) ? r2 : (__expf(r2) - 1.f);
    r3 = (r3 > 0.f) ? r3 : (__expf(r3) - 1.f);
    f16x2 o0 = (f16x2){(f16)r0, (f16)r1};
    f16x2 o1 = (f16x2){(f16)r2, (f16)r3};
    *(uint2*)outp = make_uint2(__builtin_bit_cast(unsigned, o0), __builtin_bit_cast(unsigned, o1));
}

// ---------------- layer-2 aggregate: one wave per node, 64 features, fp16 H2 ----------------
__global__ __launch_bounds__(256) void agg_l2(const int* __restrict__ rowst, const int* __restrict__ edged,
                                              const float* __restrict__ s1, const float* __restrict__ s2,
                                              const f16* __restrict__ H, float* __restrict__ outp, int N) {
    __shared__ float wls[4][64];
    __shared__ int dls[4][64];
    const int t = threadIdx.x, lane = t & 63, wave = t >> 6;
    const int node = blockIdx.x * 4 + wave;
    if (node >= N) return;
    const int beg = rowst[node], end = rowst[node + 1];
    const int deg = end - beg;
    if (deg == 0) { outp[(size_t)node * 64 + lane] = 0.f; return; }
    const float s1v = s1[node];

    float acc = 0.f;
    if (deg <= 64) {
        int d = 0;
        if (lane < deg) d = edged[beg + lane];
        dls[wave][lane] = d;
        float z = s1v + s2[d];
        float sc = (lane < deg) ? nlrelu(z) : -3e38f;
        float m = sc;
#pragma unroll
        for (int off = 32; off > 0; off >>= 1) m = fmaxf(m, __shfl_xor(m, off));
        float ex = (lane < deg) ? __expf(sc - m) : 0.f;
        float sm = ex;
#pragma unroll
        for (int off = 32; off > 0; off >>= 1) sm += __shfl_xor(sm, off);
        wls[wave][lane] = ex / sm;
        int e = 0;
        for (; e + 4 <= deg; e += 4) {
            int d0 = dls[wave][e], d1 = dls[wave][e + 1], d2 = dls[wave][e + 2], d3 = dls[wave][e + 3];
            float h0 = (float)H[(size_t)d0 * 64 + lane];
            float h1 = (float)H[(size_t)d1 * 64 + lane];
            float h2 = (float)H[(size_t)d2 * 64 + lane];
            float h3 = (float)H[(size_t)d3 * 64 + lane];
            acc += wls[wave][e] * h0 + wls[wave][e + 1] * h1 + wls[wave][e + 2] * h2 + wls[wave][e + 3] * h3;
        }
        for (; e < deg; e++)
            acc += wls[wave][e] * (float)H[(size_t)dls[wave][e] * 64 + lane];
    } else {
        float m = -3e38f;
        for (int e = beg + lane; e < end; e += 64) {
            int d = edged[e];
            m = fmaxf(m, nlrelu(s1v + s2[d]));
        }
#pragma unroll
        for (int off = 32; off > 0; off >>= 1) m = fmaxf(m, __shfl_xor(m, off));
        float sm = 0.f;
        for (int e = beg + lane; e < end; e += 64) {
            int d = edged[e];
            sm += __expf(nlrelu(s1v + s2[d]) - m);
        }
#pragma unroll
        for (int off = 32; off > 0; off >>= 1) sm += __shfl_xor(sm, off);
        float inv = 1.f / sm;
        for (int e = beg; e < end; e++) {
            int dd = edged[e];
            float w = __expf(nlrelu(s1v + s2[dd]) - m) * inv;
            acc += w * (float)H[(size_t)dd * 64 + lane];
        }
    }
    outp[(size_t)node * 64 + lane] = acc;
}

extern "C" void kernel_launch(void* const* d_in, const int* in_sizes, int n_in,
                              void* d_out, int out_size, void* d_ws, size_t ws_size,
                              hipStream_t stream) {
    const float* x     = (const float*)d_in[0];
    const int*   ei    = (const int*)d_in[1];     // [2][E] int32
    const float* Wh    = (const float*)d_in[2];
    const float* attnH = (const float*)d_in[3];
    const float* Wo    = (const float*)d_in[4];
    const float* attnO = (const float*)d_in[5];
    float* out         = (float*)d_out;

    const int N = in_sizes[0] / 128;    // 50000
    const int E = in_sizes[1] / 2;      // 800000
    const int* srcp = ei;
    const int* dstp = ei + E;

    // workspace carve (single plan, ~63 MB)
    char* base = (char*)d_ws;
    size_t off = 0;
    auto take = [&](size_t b) { void* p = base + off; off += (b + 255) & ~(size_t)255; return p; };
    f16*   B1     = (f16*)  take(32768 * 2);
    f16*   B2     = (f16*)  take(16384 * 2);
    int*   counts = (int*)  take((size_t)N * 4);
    int*   cursor = (int*)  take((size_t)N * 4);
    int*   rowst  = (int*)  take((size_t)(N + 1) * 4);
    int*   edged  = (int*)  take((size_t)E * 4);
    int*   bsum   = (int*)  take(4096);
    float* s1     = (float*)take((size_t)N * 4 * 4);
    float* s2     = (float*)take((size_t)N * 4 * 4);
    float* s1b    = (float*)take((size_t)N * 4);
    float* s2b    = (float*)take((size_t)N * 4);
    f16*   H1     = (f16*)  take((size_t)N * 256 * 2);
    f16*   hcat   = (f16*)  take((size_t)N * 256 * 2);
    f16*   H2     = (f16*)  take((size_t)N * 64 * 2);

    const int zb = (N + 255) / 256;
    k_init<<<192 + zb, 256, 0, stream>>>(Wh, Wo, B1, B2, counts, cursor, N);

    count_edges<<<(E + 255) / 256, 256, 0, stream>>>(srcp, counts, E, N);
    const int nb = (N + 1023) / 1024;
    scan_p1<<<nb, 1024, 0, stream>>>(counts, rowst, bsum, N);
    scan_p3<<<(N + 256) / 256, 256, 0, stream>>>(bsum, rowst, N, nb);

    const int Gg = (N + 63) / 64;                 // gemm1 blocks
    const int Gs = (E + 255) / 256;               // scatter blocks
    k_scatter_gemm1<<<Gg + Gs, 256, 0, stream>>>(srcp, dstp, rowst, cursor, edged,
                                                 x, B1, attnH, H1, s1, s2, N, E, N, Gg);

    agg_l1<<<(N + 3) / 4, 256, 0, stream>>>(rowst, edged, s1, s2, H1, hcat, N);
    gemm2_f16<<<Gg, 256, 0, stream>>>(hcat, B2, attnO, H2, s1b, s2b, N);
    agg_l2<<<(N + 3) / 4, 256, 0, stream>>>(rowst, edged, s1b, s2b, H2, out, N);
}

// Round 8
// 262.875 us; speedup vs baseline: 3.1201x; 1.0523x over previous
//
#include <hip/hip_runtime.h>

typedef unsigned short u16;
typedef _Float16 f16;
typedef __attribute__((ext_vector_type(8))) _Float16 f16x8;
typedef __attribute__((ext_vector_type(2))) _Float16 f16x2;
typedef __attribute__((ext_vector_type(4))) float f32x4;

__device__ inline float nlrelu(float z) { return (z > 0.f) ? -z : -0.01f * z; }  // -leaky_relu
__device__ inline float4 score4(float4 a, float4 b) {
    return make_float4(nlrelu(a.x + b.x), nlrelu(a.y + b.y), nlrelu(a.z + b.z), nlrelu(a.w + b.w));
}
__device__ inline unsigned packdup(float w) {
    f16x2 p = (f16x2){(f16)w, (f16)w};
    return __builtin_bit_cast(unsigned, p);
}

// ---------------- K1: weight frags (fp16) + zero counts ----------------
__global__ void k_init(const float* __restrict__ Wh, const float* __restrict__ Wo,
                       f16* __restrict__ B1, f16* __restrict__ B2,
                       int* __restrict__ counts, int N) {
    const int b = blockIdx.x;
    if (b < 128) {                       // W1 frag: 32768 elems
        int i = b * 256 + threadIdx.x;
        int j = i & 7, lane = (i >> 3) & 63, kg = (i >> 9) & 3, nt = i >> 11;
        int n = nt * 16 + (lane & 15);
        int k = kg * 32 + ((lane >> 4) << 3) + j;
        B1[i] = (f16)Wh[(n >> 6) * (128 * 64) + k * 64 + (n & 63)];
    } else if (b < 192) {                // W2 frag: 16384 elems
        int i = (b - 128) * 256 + threadIdx.x;
        int j = i & 7, lane = (i >> 3) & 63, kg = (i >> 9) & 7, nt = i >> 12;
        int n = nt * 16 + (lane & 15);
        int k = kg * 32 + ((lane >> 4) << 3) + j;
        B2[i] = (f16)Wo[k * 64 + n];
    } else {
        int i = (b - 192) * 256 + threadIdx.x;
        if (i < N) counts[i] = 0;
    }
}

// ---------------- single-atomic-pass CSR: counts + per-edge position ----------------
// block b handles edges [b*1024, b*1024+1024), thread t does 4 strided → 4 atomic chains in flight
__global__ __launch_bounds__(256) void count_pos(const int* __restrict__ src, int* __restrict__ counts,
                                                 int* __restrict__ pos, int E, int N) {
    const int base = blockIdx.x * 1024 + threadIdx.x;
#pragma unroll
    for (int j = 0; j < 4; j++) {
        int e = base + j * 256;
        if (e < E) {
            int s = src[e];
            s = ((unsigned)s < (unsigned)N) ? s : 0;
            pos[e] = atomicAdd(&counts[s], 1);
        }
    }
}

__global__ __launch_bounds__(1024) void scan_p1(const int* __restrict__ counts, int* __restrict__ rowst,
                                                int* __restrict__ bsum, int n) {
    const int t = threadIdx.x, lane = t & 63, w = t >> 6;
    __shared__ int wsum[16];
    int i = blockIdx.x * 1024 + t;
    int v = (i < n) ? counts[i] : 0;
    int orig = v;
    for (int d = 1; d < 64; d <<= 1) { int x = __shfl_up(v, d); if (lane >= d) v += x; }
    if (lane == 63) wsum[w] = v;
    __syncthreads();
    if (t == 0) {
        int acc = 0;
        for (int j = 0; j < 16; j++) { int tmp = wsum[j]; wsum[j] = acc; acc += tmp; }
        bsum[blockIdx.x] = acc;
    }
    __syncthreads();
    if (i < n) rowst[i] = wsum[w] + (v - orig);   // local (per-1024-group) exclusive prefix
}

__global__ void scan_p3(const int* __restrict__ bsum, int* __restrict__ rowst, int n, int nb) {
    __shared__ int sh_pre, sh_tot;
    const int i = blockIdx.x * 256 + threadIdx.x;
    const int g = (blockIdx.x * 256) >> 10;
    if (threadIdx.x == 0) {
        int acc = 0, pre = 0;
        for (int j = 0; j < nb; j++) { if (j == g) pre = acc; acc += bsum[j]; }
        if (g >= nb) pre = acc;
        sh_pre = pre; sh_tot = acc;
    }
    __syncthreads();
    if (i < n) rowst[i] += sh_pre;
    else if (i == n) rowst[n] = sh_tot;
}

// ---------------- scatter WITHOUT atomics: edged[rowst[s]+pos[e]] = dst[e] ----------------
__global__ __launch_bounds__(256) void scatter_noat(const int* __restrict__ src, const int* __restrict__ dst,
                                                    const int* __restrict__ rowst, const int* __restrict__ pos,
                                                    int* __restrict__ edged, int E, int N) {
    const int base = blockIdx.x * 1024 + threadIdx.x;
#pragma unroll
    for (int j = 0; j < 4; j++) {
        int e = base + j * 256;
        if (e < E) {
            int s = src[e];
            s = ((unsigned)s < (unsigned)N) ? s : 0;
            int d = dst[e];
            d = ((unsigned)d < (unsigned)N) ? d : 0;
            edged[rowst[s] + pos[e]] = d;
        }
    }
}

// ---------------- gemm1 (f16 MFMA): H1[Mx256] = X[Mx128] @ W1^T, fused s1/s2 ----------------
__global__ __launch_bounds__(256) void gemm1_f16(const float* __restrict__ X, const f16* __restrict__ B1,
        const float* __restrict__ attnH,
        f16* __restrict__ H1, float* __restrict__ s1, float* __restrict__ s2, int M) {
    const int lane = threadIdx.x & 63, wave = threadIdx.x >> 6;
    const int row0 = (blockIdx.x * 4 + wave) * 16;
    if (row0 >= M) return;
    const int mrow = row0 + (lane & 15);
    const int koff = (lane >> 4) * 8;
    const float* aptr = X + (size_t)mrow * 128 + koff;

    f32x4 acc[16];
#pragma unroll
    for (int c = 0; c < 16; c++) acc[c] = (f32x4){0.f, 0.f, 0.f, 0.f};

#pragma unroll
    for (int kg = 0; kg < 4; kg++) {
        float av[8];
        *(float4*)av       = *(const float4*)(aptr + kg * 32);
        *(float4*)(av + 4) = *(const float4*)(aptr + kg * 32 + 4);
        f16x8 a;
#pragma unroll
        for (int j = 0; j < 8; j++) a[j] = (f16)av[j];
#pragma unroll
        for (int nt = 0; nt < 16; nt++) {
            const size_t bidx = (size_t)(((nt << 2) + kg) * 64 + lane) * 8;
            f16x8 bfr = *(const f16x8*)(B1 + bidx);
            acc[nt] = __builtin_amdgcn_mfma_f32_16x16x32_f16(a, bfr, acc[nt], 0, 0, 0);
        }
    }
    const int rbase = (lane >> 4) * 4;
    const int colq = lane & 15;
#pragma unroll
    for (int h = 0; h < 4; h++) {
        float s1a[4] = {0.f, 0.f, 0.f, 0.f}, s2a[4] = {0.f, 0.f, 0.f, 0.f};
#pragma unroll
        for (int q = 0; q < 4; q++) {
            const int nt = h * 4 + q;
            const int col = nt * 16 + colq;
            const float a1v = attnH[h * 128 + (col & 63)];
            const float a2v = attnH[h * 128 + 64 + (col & 63)];
#pragma unroll
            for (int r = 0; r < 4; r++) {
                float c = acc[nt][r];
                H1[(size_t)(row0 + rbase + r) * 256 + col] = (f16)c;
                s1a[r] += c * a1v;
                s2a[r] += c * a2v;
            }
        }
#pragma unroll
        for (int off = 1; off < 16; off <<= 1)
#pragma unroll
            for (int r = 0; r < 4; r++) {
                s1a[r] += __shfl_xor(s1a[r], off);
                s2a[r] += __shfl_xor(s2a[r], off);
            }
        if (colq == 0)
#pragma unroll
            for (int r = 0; r < 4; r++) {
                s1[(size_t)(row0 + rbase + r) * 4 + h] = s1a[r];
                s2[(size_t)(row0 + rbase + r) * 4 + h] = s2a[r];
            }
    }
}

// ---------------- gemm2 (f16 MFMA): H2[Mx64] = hcat[Mx256] @ W2^T, fused s1b/s2b ----------------
__global__ __launch_bounds__(256) void gemm2_f16(const f16* __restrict__ Hc, const f16* __restrict__ B2,
        const float* __restrict__ attnO,
        f16* __restrict__ H2, float* __restrict__ s1b, float* __restrict__ s2b, int M) {
    const int lane = threadIdx.x & 63, wave = threadIdx.x >> 6;
    const int row0 = (blockIdx.x * 4 + wave) * 16;
    if (row0 >= M) return;
    const int mrow = row0 + (lane & 15);
    const int koff = (lane >> 4) * 8;
    const f16* ap = Hc + (size_t)mrow * 256 + koff;

    f32x4 acc[4];
#pragma unroll
    for (int c = 0; c < 4; c++) acc[c] = (f32x4){0.f, 0.f, 0.f, 0.f};

#pragma unroll
    for (int kg = 0; kg < 8; kg++) {
        f16x8 a = *(const f16x8*)(ap + kg * 32);
#pragma unroll
        for (int nt = 0; nt < 4; nt++) {
            const size_t bidx = (size_t)(((nt << 3) + kg) * 64 + lane) * 8;
            f16x8 bfr = *(const f16x8*)(B2 + bidx);
            acc[nt] = __builtin_amdgcn_mfma_f32_16x16x32_f16(a, bfr, acc[nt], 0, 0, 0);
        }
    }
    const int rbase = (lane >> 4) * 4;
    const int colq = lane & 15;
    float s1a[4] = {0.f, 0.f, 0.f, 0.f}, s2a[4] = {0.f, 0.f, 0.f, 0.f};
#pragma unroll
    for (int nt = 0; nt < 4; nt++) {
        const int col = nt * 16 + colq;
        const float a1v = attnO[col];
        const float a2v = attnO[64 + col];
#pragma unroll
        for (int r = 0; r < 4; r++) {
            float c = acc[nt][r];
            H2[(size_t)(row0 + rbase + r) * 64 + col] = (f16)c;
            s1a[r] += c * a1v;
            s2a[r] += c * a2v;
        }
    }
#pragma unroll
    for (int off = 1; off < 16; off <<= 1)
#pragma unroll
        for (int r = 0; r < 4; r++) {
            s1a[r] += __shfl_xor(s1a[r], off);
            s2a[r] += __shfl_xor(s2a[r], off);
        }
    if (colq == 0)
#pragma unroll
        for (int r = 0; r < 4; r++) {
            s1b[row0 + rbase + r] = s1a[r];
            s2b[row0 + rbase + r] = s2a[r];
        }
}

// ---------------- layer-1 aggregate: one wave per node, pk_fma_f16 gather ----------------
__global__ __launch_bounds__(256) void agg_l1(const int* __restrict__ rowst, const int* __restrict__ edged,
                                              const float* __restrict__ s1, const float* __restrict__ s2,
                                              const f16* __restrict__ H, f16* __restrict__ hcat, int N) {
    __shared__ unsigned wls[4][64][4];
    __shared__ int dls[4][64];
    const int t = threadIdx.x, lane = t & 63, wave = t >> 6;
    const int node = blockIdx.x * 4 + wave;
    if (node >= N) return;
    const int beg = rowst[node], end = rowst[node + 1];
    const int deg = end - beg;
    const int head = lane >> 4;
    f16* outp = hcat + (size_t)node * 256 + lane * 4;
    if (deg == 0) { *(uint2*)outp = make_uint2(0u, 0u); return; }
    const float4 s1v = *(const float4*)(s1 + (size_t)node * 4);

    float r0, r1, r2, r3;
    if (deg <= 64) {
        int d = 0;
        if (lane < deg) d = edged[beg + lane];
        dls[wave][lane] = d;
        float4 s2v = *(const float4*)(s2 + (size_t)d * 4);
        float4 sc = score4(s1v, s2v);
        if (lane >= deg) sc = make_float4(-3e38f, -3e38f, -3e38f, -3e38f);
        float4 m = sc;
#pragma unroll
        for (int off = 32; off > 0; off >>= 1) {
            m.x = fmaxf(m.x, __shfl_xor(m.x, off));
            m.y = fmaxf(m.y, __shfl_xor(m.y, off));
            m.z = fmaxf(m.z, __shfl_xor(m.z, off));
            m.w = fmaxf(m.w, __shfl_xor(m.w, off));
        }
        float4 ex = make_float4(0.f, 0.f, 0.f, 0.f);
        if (lane < deg) ex = make_float4(__expf(sc.x - m.x), __expf(sc.y - m.y),
                                         __expf(sc.z - m.z), __expf(sc.w - m.w));
        float4 sm = ex;
#pragma unroll
        for (int off = 32; off > 0; off >>= 1) {
            sm.x += __shfl_xor(sm.x, off);
            sm.y += __shfl_xor(sm.y, off);
            sm.z += __shfl_xor(sm.z, off);
            sm.w += __shfl_xor(sm.w, off);
        }
        wls[wave][lane][0] = packdup(ex.x / sm.x);
        wls[wave][lane][1] = packdup(ex.y / sm.y);
        wls[wave][lane][2] = packdup(ex.z / sm.z);
        wls[wave][lane][3] = packdup(ex.w / sm.w);
        f16x2 a01[4], a23[4];
#pragma unroll
        for (int j = 0; j < 4; j++) { a01[j] = (f16x2)(f16)0.f; a23[j] = (f16x2)(f16)0.f; }
        int e = 0;
        for (; e + 4 <= deg; e += 4) {
#pragma unroll
            for (int j = 0; j < 4; j++) {
                int dd = dls[wave][e + j];
                uint2 raw = *(const uint2*)(H + (size_t)dd * 256 + lane * 4);
                f16x2 lo = __builtin_bit_cast(f16x2, raw.x);
                f16x2 hi = __builtin_bit_cast(f16x2, raw.y);
                f16x2 w2 = __builtin_bit_cast(f16x2, wls[wave][e + j][head]);
                a01[j] += w2 * lo;
                a23[j] += w2 * hi;
            }
        }
        for (; e < deg; e++) {
            int dd = dls[wave][e];
            uint2 raw = *(const uint2*)(H + (size_t)dd * 256 + lane * 4);
            f16x2 lo = __builtin_bit_cast(f16x2, raw.x);
            f16x2 hi = __builtin_bit_cast(f16x2, raw.y);
            f16x2 w2 = __builtin_bit_cast(f16x2, wls[wave][e][head]);
            a01[0] += w2 * lo;
            a23[0] += w2 * hi;
        }
        r0 = (float)a01[0][0] + (float)a01[1][0] + (float)a01[2][0] + (float)a01[3][0];
        r1 = (float)a01[0][1] + (float)a01[1][1] + (float)a01[2][1] + (float)a01[3][1];
        r2 = (float)a23[0][0] + (float)a23[1][0] + (float)a23[2][0] + (float)a23[3][0];
        r3 = (float)a23[0][1] + (float)a23[1][1] + (float)a23[2][1] + (float)a23[3][1];
    } else {
        float4 m = make_float4(-3e38f, -3e38f, -3e38f, -3e38f);
        for (int e = beg + lane; e < end; e += 64) {
            int d = edged[e];
            float4 sc = score4(s1v, *(const float4*)(s2 + (size_t)d * 4));
            m.x = fmaxf(m.x, sc.x); m.y = fmaxf(m.y, sc.y); m.z = fmaxf(m.z, sc.z); m.w = fmaxf(m.w, sc.w);
        }
#pragma unroll
        for (int off = 32; off > 0; off >>= 1) {
            m.x = fmaxf(m.x, __shfl_xor(m.x, off));
            m.y = fmaxf(m.y, __shfl_xor(m.y, off));
            m.z = fmaxf(m.z, __shfl_xor(m.z, off));
            m.w = fmaxf(m.w, __shfl_xor(m.w, off));
        }
        float4 sm = make_float4(0.f, 0.f, 0.f, 0.f);
        for (int e = beg + lane; e < end; e += 64) {
            int d = edged[e];
            float4 sc = score4(s1v, *(const float4*)(s2 + (size_t)d * 4));
            sm.x += __expf(sc.x - m.x); sm.y += __expf(sc.y - m.y);
            sm.z += __expf(sc.z - m.z); sm.w += __expf(sc.w - m.w);
        }
#pragma unroll
        for (int off = 32; off > 0; off >>= 1) {
            sm.x += __shfl_xor(sm.x, off);
            sm.y += __shfl_xor(sm.y, off);
            sm.z += __shfl_xor(sm.z, off);
            sm.w += __shfl_xor(sm.w, off);
        }
        float4 inv = make_float4(1.f / sm.x, 1.f / sm.y, 1.f / sm.z, 1.f / sm.w);
        float4 acc = make_float4(0.f, 0.f, 0.f, 0.f);
        for (int e = beg; e < end; e++) {
            int dd = edged[e];
            float4 sc = score4(s1v, *(const float4*)(s2 + (size_t)dd * 4));
            float wv[4] = { __expf(sc.x - m.x) * inv.x, __expf(sc.y - m.y) * inv.y,
                            __expf(sc.z - m.z) * inv.z, __expf(sc.w - m.w) * inv.w };
            float w = (head == 0) ? wv[0] : (head == 1) ? wv[1] : (head == 2) ? wv[2] : wv[3];
            const f16* hp = H + (size_t)dd * 256 + lane * 4;
            acc.x += w * (float)hp[0]; acc.y += w * (float)hp[1];
            acc.z += w * (float)hp[2]; acc.w += w * (float)hp[3];
        }
        r0 = acc.x; r1 = acc.y; r2 = acc.z; r3 = acc.w;
    }
    r0 = (r0 > 0.f) ? r0 : (__expf(r0) - 1.f);
    r1 = (r1 > 0.f) ? r1 : (__expf(r1) - 1.f);
    r2 = (r2 > 0.f) ? r2 : (__expf(r2) - 1.f);
    r3 = (r3 > 0.f) ? r3 : (__expf(r3) - 1.f);
    f16x2 o0 = (f16x2){(f16)r0, (f16)r1};
    f16x2 o1 = (f16x2){(f16)r2, (f16)r3};
    *(uint2*)outp = make_uint2(__builtin_bit_cast(unsigned, o0), __builtin_bit_cast(unsigned, o1));
}

// ---------------- layer-2 aggregate ----------------
__global__ __launch_bounds__(256) void agg_l2(const int* __restrict__ rowst, const int* __restrict__ edged,
                                              const float* __restrict__ s1, const float* __restrict__ s2,
                                              const f16* __restrict__ H, float* __restrict__ outp, int N) {
    __shared__ float wls[4][64];
    __shared__ int dls[4][64];
    const int t = threadIdx.x, lane = t & 63, wave = t >> 6;
    const int node = blockIdx.x * 4 + wave;
    if (node >= N) return;
    const int beg = rowst[node], end = rowst[node + 1];
    const int deg = end - beg;
    if (deg == 0) { outp[(size_t)node * 64 + lane] = 0.f; return; }
    const float s1v = s1[node];

    float acc = 0.f;
    if (deg <= 64) {
        int d = 0;
        if (lane < deg) d = edged[beg + lane];
        dls[wave][lane] = d;
        float z = s1v + s2[d];
        float sc = (lane < deg) ? nlrelu(z) : -3e38f;
        float m = sc;
#pragma unroll
        for (int off = 32; off > 0; off >>= 1) m = fmaxf(m, __shfl_xor(m, off));
        float ex = (lane < deg) ? __expf(sc - m) : 0.f;
        float sm = ex;
#pragma unroll
        for (int off = 32; off > 0; off >>= 1) sm += __shfl_xor(sm, off);
        wls[wave][lane] = ex / sm;
        int e = 0;
        for (; e + 4 <= deg; e += 4) {
            int d0 = dls[wave][e], d1 = dls[wave][e + 1], d2 = dls[wave][e + 2], d3 = dls[wave][e + 3];
            float h0 = (float)H[(size_t)d0 * 64 + lane];
            float h1 = (float)H[(size_t)d1 * 64 + lane];
            float h2 = (float)H[(size_t)d2 * 64 + lane];
            float h3 = (float)H[(size_t)d3 * 64 + lane];
            acc += wls[wave][e] * h0 + wls[wave][e + 1] * h1 + wls[wave][e + 2] * h2 + wls[wave][e + 3] * h3;
        }
        for (; e < deg; e++)
            acc += wls[wave][e] * (float)H[(size_t)dls[wave][e] * 64 + lane];
    } else {
        float m = -3e38f;
        for (int e = beg + lane; e < end; e += 64) {
            int d = edged[e];
            m = fmaxf(m, nlrelu(s1v + s2[d]));
        }
#pragma unroll
        for (int off = 32; off > 0; off >>= 1) m = fmaxf(m, __shfl_xor(m, off));
        float sm = 0.f;
        for (int e = beg + lane; e < end; e += 64) {
            int d = edged[e];
            sm += __expf(nlrelu(s1v + s2[d]) - m);
        }
#pragma unroll
        for (int off = 32; off > 0; off >>= 1) sm += __shfl_xor(sm, off);
        float inv = 1.f / sm;
        for (int e = beg; e < end; e++) {
            int dd = edged[e];
            float w = __expf(nlrelu(s1v + s2[dd]) - m) * inv;
            acc += w * (float)H[(size_t)dd * 64 + lane];
        }
    }
    outp[(size_t)node * 64 + lane] = acc;
}

extern "C" void kernel_launch(void* const* d_in, const int* in_sizes, int n_in,
                              void* d_out, int out_size, void* d_ws, size_t ws_size,
                              hipStream_t stream) {
    const float* x     = (const float*)d_in[0];
    const int*   ei    = (const int*)d_in[1];     // [2][E] int32
    const float* Wh    = (const float*)d_in[2];
    const float* attnH = (const float*)d_in[3];
    const float* Wo    = (const float*)d_in[4];
    const float* attnO = (const float*)d_in[5];
    float* out         = (float*)d_out;

    const int N = in_sizes[0] / 128;    // 50000
    const int E = in_sizes[1] / 2;      // 800000
    const int* srcp = ei;
    const int* dstp = ei + E;

    char* base = (char*)d_ws;
    size_t off = 0;
    auto take = [&](size_t b) { void* p = base + off; off += (b + 255) & ~(size_t)255; return p; };
    f16*   B1     = (f16*)  take(32768 * 2);
    f16*   B2     = (f16*)  take(16384 * 2);
    int*   counts = (int*)  take((size_t)N * 4);
    int*   rowst  = (int*)  take((size_t)(N + 1) * 4);
    int*   pos    = (int*)  take((size_t)E * 4);
    int*   edged  = (int*)  take((size_t)E * 4);
    int*   bsum   = (int*)  take(4096);
    float* s1     = (float*)take((size_t)N * 4 * 4);
    float* s2     = (float*)take((size_t)N * 4 * 4);
    float* s1b    = (float*)take((size_t)N * 4);
    float* s2b    = (float*)take((size_t)N * 4);
    f16*   H1     = (f16*)  take((size_t)N * 256 * 2);
    f16*   hcat   = (f16*)  take((size_t)N * 256 * 2);
    f16*   H2     = (f16*)  take((size_t)N * 64 * 2);

    const int zb = (N + 255) / 256;
    k_init<<<192 + zb, 256, 0, stream>>>(Wh, Wo, B1, B2, counts, N);

    const int eb4 = (E + 1023) / 1024;
    count_pos<<<eb4, 256, 0, stream>>>(srcp, counts, pos, E, N);

    const int nb = (N + 1023) / 1024;
    scan_p1<<<nb, 1024, 0, stream>>>(counts, rowst, bsum, N);
    scan_p3<<<(N + 256) / 256, 256, 0, stream>>>(bsum, rowst, N, nb);

    scatter_noat<<<eb4, 256, 0, stream>>>(srcp, dstp, rowst, pos, edged, E, N);

    const int Gg = (N + 63) / 64;
    gemm1_f16<<<Gg, 256, 0, stream>>>(x, B1, attnH, H1, s1, s2, N);
    agg_l1<<<(N + 3) / 4, 256, 0, stream>>>(rowst, edged, s1, s2, H1, hcat, N);
    gemm2_f16<<<Gg, 256, 0, stream>>>(hcat, B2, attnO, H2, s1b, s2b, N);
    agg_l2<<<(N + 3) / 4, 256, 0, stream>>>(rowst, edged, s1b, s2b, H2, out, N);
}

// Round 9
// 257.214 us; speedup vs baseline: 3.1888x; 1.0220x over previous
//
#include <hip/hip_runtime.h>

typedef unsigned short u16;
typedef _Float16 f16;
typedef __attribute__((ext_vector_type(8))) _Float16 f16x8;
typedef __attribute__((ext_vector_type(2))) _Float16 f16x2;
typedef __attribute__((ext_vector_type(4))) float f32x4;

__device__ inline float nlrelu(float z) { return (z > 0.f) ? -z : -0.01f * z; }  // -leaky_relu
__device__ inline float4 score4(float4 a, float4 b) {
    return make_float4(nlrelu(a.x + b.x), nlrelu(a.y + b.y), nlrelu(a.z + b.z), nlrelu(a.w + b.w));
}
__device__ inline unsigned packdup(float w) {
    f16x2 p = (f16x2){(f16)w, (f16)w};
    return __builtin_bit_cast(unsigned, p);
}

// ---------------- K1: weight frags (fp16) + count+pos in one kernel ----------------
// blocks [0,128): W1 frag; [128,192): W2 frag; [192, 192+eb4): count_pos (4 edges/thread)
__global__ __launch_bounds__(256) void k_initcnt(const float* __restrict__ Wh, const float* __restrict__ Wo,
                       f16* __restrict__ B1, f16* __restrict__ B2,
                       const int* __restrict__ src, int* __restrict__ counts, int* __restrict__ pos,
                       int E, int N) {
    const int b = blockIdx.x;
    if (b < 128) {                       // W1 frag: 32768 elems
        int i = b * 256 + threadIdx.x;
        int j = i & 7, lane = (i >> 3) & 63, kg = (i >> 9) & 3, nt = i >> 11;
        int n = nt * 16 + (lane & 15);
        int k = kg * 32 + ((lane >> 4) << 3) + j;
        B1[i] = (f16)Wh[(n >> 6) * (128 * 64) + k * 64 + (n & 63)];
    } else if (b < 192) {                // W2 frag: 16384 elems
        int i = (b - 128) * 256 + threadIdx.x;
        int j = i & 7, lane = (i >> 3) & 63, kg = (i >> 9) & 7, nt = i >> 12;
        int n = nt * 16 + (lane & 15);
        int k = kg * 32 + ((lane >> 4) << 3) + j;
        B2[i] = (f16)Wo[k * 64 + n];
    } else {                             // count + position assignment, 4 chains in flight
        const int base = (b - 192) * 1024 + threadIdx.x;
#pragma unroll
        for (int j = 0; j < 4; j++) {
            int e = base + j * 256;
            if (e < E) {
                int s = src[e];
                s = ((unsigned)s < (unsigned)N) ? s : 0;
                pos[e] = atomicAdd(&counts[s], 1);
            }
        }
    }
}

// ---------------- single-pass scan with atomic-ticket block base ----------------
// rowst[i] = global base (arrival-order segment) + local exclusive prefix. End = rowst[i]+counts[i].
__global__ __launch_bounds__(1024) void scan_ticket(const int* __restrict__ counts, int* __restrict__ rowst,
                                                    int* __restrict__ cursor, int n) {
    const int t = threadIdx.x, lane = t & 63, w = t >> 6;
    __shared__ int wsum[16];
    __shared__ int sh_base;
    int i = blockIdx.x * 1024 + t;
    int v = (i < n) ? counts[i] : 0;
    int orig = v;
    for (int d = 1; d < 64; d <<= 1) { int x = __shfl_up(v, d); if (lane >= d) v += x; }
    if (lane == 63) wsum[w] = v;
    __syncthreads();
    if (t == 0) {
        int acc = 0;
        for (int j = 0; j < 16; j++) { int tmp = wsum[j]; wsum[j] = acc; acc += tmp; }
        sh_base = atomicAdd(cursor, acc);       // claim this block's segment
    }
    __syncthreads();
    if (i < n) rowst[i] = sh_base + wsum[w] + (v - orig);
}

// ---------------- scatter WITHOUT atomics ----------------
__global__ __launch_bounds__(256) void scatter_noat(const int* __restrict__ src, const int* __restrict__ dst,
                                                    const int* __restrict__ rowst, const int* __restrict__ pos,
                                                    int* __restrict__ edged, int E, int N) {
    const int base = blockIdx.x * 1024 + threadIdx.x;
#pragma unroll
    for (int j = 0; j < 4; j++) {
        int e = base + j * 256;
        if (e < E) {
            int s = src[e];
            s = ((unsigned)s < (unsigned)N) ? s : 0;
            int d = dst[e];
            d = ((unsigned)d < (unsigned)N) ? d : 0;
            edged[rowst[s] + pos[e]] = d;
        }
    }
}

// ---------------- gemm1 (f16 MFMA): H1[Mx256] = X[Mx128] @ W1^T, fused s1/s2 ----------------
__global__ __launch_bounds__(256) void gemm1_f16(const float* __restrict__ X, const f16* __restrict__ B1,
        const float* __restrict__ attnH,
        f16* __restrict__ H1, float* __restrict__ s1, float* __restrict__ s2, int M) {
    const int lane = threadIdx.x & 63, wave = threadIdx.x >> 6;
    const int row0 = (blockIdx.x * 4 + wave) * 16;
    if (row0 >= M) return;
    const int mrow = row0 + (lane & 15);
    const int koff = (lane >> 4) * 8;
    const float* aptr = X + (size_t)mrow * 128 + koff;

    f32x4 acc[16];
#pragma unroll
    for (int c = 0; c < 16; c++) acc[c] = (f32x4){0.f, 0.f, 0.f, 0.f};

#pragma unroll
    for (int kg = 0; kg < 4; kg++) {
        float av[8];
        *(float4*)av       = *(const float4*)(aptr + kg * 32);
        *(float4*)(av + 4) = *(const float4*)(aptr + kg * 32 + 4);
        f16x8 a;
#pragma unroll
        for (int j = 0; j < 8; j++) a[j] = (f16)av[j];
#pragma unroll
        for (int nt = 0; nt < 16; nt++) {
            const size_t bidx = (size_t)(((nt << 2) + kg) * 64 + lane) * 8;
            f16x8 bfr = *(const f16x8*)(B1 + bidx);
            acc[nt] = __builtin_amdgcn_mfma_f32_16x16x32_f16(a, bfr, acc[nt], 0, 0, 0);
        }
    }
    const int rbase = (lane >> 4) * 4;
    const int colq = lane & 15;
#pragma unroll
    for (int h = 0; h < 4; h++) {
        float s1a[4] = {0.f, 0.f, 0.f, 0.f}, s2a[4] = {0.f, 0.f, 0.f, 0.f};
#pragma unroll
        for (int q = 0; q < 4; q++) {
            const int nt = h * 4 + q;
            const int col = nt * 16 + colq;
            const float a1v = attnH[h * 128 + (col & 63)];
            const float a2v = attnH[h * 128 + 64 + (col & 63)];
#pragma unroll
            for (int r = 0; r < 4; r++) {
                float c = acc[nt][r];
                H1[(size_t)(row0 + rbase + r) * 256 + col] = (f16)c;
                s1a[r] += c * a1v;
                s2a[r] += c * a2v;
            }
        }
#pragma unroll
        for (int off = 1; off < 16; off <<= 1)
#pragma unroll
            for (int r = 0; r < 4; r++) {
                s1a[r] += __shfl_xor(s1a[r], off);
                s2a[r] += __shfl_xor(s2a[r], off);
            }
        if (colq == 0)
#pragma unroll
            for (int r = 0; r < 4; r++) {
                s1[(size_t)(row0 + rbase + r) * 4 + h] = s1a[r];
                s2[(size_t)(row0 + rbase + r) * 4 + h] = s2a[r];
            }
    }
}

// ---------------- gemm2 (f16 MFMA): H2[Mx64] = hcat[Mx256] @ W2^T, fused s1b/s2b ----------------
__global__ __launch_bounds__(256) void gemm2_f16(const f16* __restrict__ Hc, const f16* __restrict__ B2,
        const float* __restrict__ attnO,
        f16* __restrict__ H2, float* __restrict__ s1b, float* __restrict__ s2b, int M) {
    const int lane = threadIdx.x & 63, wave = threadIdx.x >> 6;
    const int row0 = (blockIdx.x * 4 + wave) * 16;
    if (row0 >= M) return;
    const int mrow = row0 + (lane & 15);
    const int koff = (lane >> 4) * 8;
    const f16* ap = Hc + (size_t)mrow * 256 + koff;

    f32x4 acc[4];
#pragma unroll
    for (int c = 0; c < 4; c++) acc[c] = (f32x4){0.f, 0.f, 0.f, 0.f};

#pragma unroll
    for (int kg = 0; kg < 8; kg++) {
        f16x8 a = *(const f16x8*)(ap + kg * 32);
#pragma unroll
        for (int nt = 0; nt < 4; nt++) {
            const size_t bidx = (size_t)(((nt << 3) + kg) * 64 + lane) * 8;
            f16x8 bfr = *(const f16x8*)(B2 + bidx);
            acc[nt] = __builtin_amdgcn_mfma_f32_16x16x32_f16(a, bfr, acc[nt], 0, 0, 0);
        }
    }
    const int rbase = (lane >> 4) * 4;
    const int colq = lane & 15;
    float s1a[4] = {0.f, 0.f, 0.f, 0.f}, s2a[4] = {0.f, 0.f, 0.f, 0.f};
#pragma unroll
    for (int nt = 0; nt < 4; nt++) {
        const int col = nt * 16 + colq;
        const float a1v = attnO[col];
        const float a2v = attnO[64 + col];
#pragma unroll
        for (int r = 0; r < 4; r++) {
            float c = acc[nt][r];
            H2[(size_t)(row0 + rbase + r) * 64 + col] = (f16)c;
            s1a[r] += c * a1v;
            s2a[r] += c * a2v;
        }
    }
#pragma unroll
    for (int off = 1; off < 16; off <<= 1)
#pragma unroll
        for (int r = 0; r < 4; r++) {
            s1a[r] += __shfl_xor(s1a[r], off);
            s2a[r] += __shfl_xor(s2a[r], off);
        }
    if (colq == 0)
#pragma unroll
        for (int r = 0; r < 4; r++) {
            s1b[row0 + rbase + r] = s1a[r];
            s2b[row0 + rbase + r] = s2a[r];
        }
}

// ---------------- layer-1 aggregate: one wave per node, pk_fma_f16 gather (unroll 8) ----------------
__global__ __launch_bounds__(256) void agg_l1(const int* __restrict__ rowst, const int* __restrict__ cnt,
                                              const int* __restrict__ edged,
                                              const float* __restrict__ s1, const float* __restrict__ s2,
                                              const f16* __restrict__ H, f16* __restrict__ hcat, int N) {
    __shared__ unsigned wls[4][64][4];
    __shared__ int dls[4][64];
    const int t = threadIdx.x, lane = t & 63, wave = t >> 6;
    const int node = blockIdx.x * 4 + wave;
    if (node >= N) return;
    const int beg = rowst[node];
    const int deg = cnt[node];
    const int end = beg + deg;
    const int head = lane >> 4;
    f16* outp = hcat + (size_t)node * 256 + lane * 4;
    if (deg == 0) { *(uint2*)outp = make_uint2(0u, 0u); return; }
    const float4 s1v = *(const float4*)(s1 + (size_t)node * 4);

    float r0, r1, r2, r3;
    if (deg <= 64) {
        int d = 0;
        if (lane < deg) d = edged[beg + lane];
        dls[wave][lane] = d;
        float4 s2v = *(const float4*)(s2 + (size_t)d * 4);
        float4 sc = score4(s1v, s2v);
        if (lane >= deg) sc = make_float4(-3e38f, -3e38f, -3e38f, -3e38f);
        float4 m = sc;
#pragma unroll
        for (int off = 32; off > 0; off >>= 1) {
            m.x = fmaxf(m.x, __shfl_xor(m.x, off));
            m.y = fmaxf(m.y, __shfl_xor(m.y, off));
            m.z = fmaxf(m.z, __shfl_xor(m.z, off));
            m.w = fmaxf(m.w, __shfl_xor(m.w, off));
        }
        float4 ex = make_float4(0.f, 0.f, 0.f, 0.f);
        if (lane < deg) ex = make_float4(__expf(sc.x - m.x), __expf(sc.y - m.y),
                                         __expf(sc.z - m.z), __expf(sc.w - m.w));
        float4 sm = ex;
#pragma unroll
        for (int off = 32; off > 0; off >>= 1) {
            sm.x += __shfl_xor(sm.x, off);
            sm.y += __shfl_xor(sm.y, off);
            sm.z += __shfl_xor(sm.z, off);
            sm.w += __shfl_xor(sm.w, off);
        }
        wls[wave][lane][0] = packdup(ex.x / sm.x);
        wls[wave][lane][1] = packdup(ex.y / sm.y);
        wls[wave][lane][2] = packdup(ex.z / sm.z);
        wls[wave][lane][3] = packdup(ex.w / sm.w);
        f16x2 a01[4], a23[4];
#pragma unroll
        for (int j = 0; j < 4; j++) { a01[j] = (f16x2)(f16)0.f; a23[j] = (f16x2)(f16)0.f; }
        int e = 0;
        for (; e + 8 <= deg; e += 8) {           // 8 gathers in flight
            uint2 raw[8];
#pragma unroll
            for (int j = 0; j < 8; j++)
                raw[j] = *(const uint2*)(H + (size_t)dls[wave][e + j] * 256 + lane * 4);
#pragma unroll
            for (int j = 0; j < 8; j++) {
                f16x2 lo = __builtin_bit_cast(f16x2, raw[j].x);
                f16x2 hi = __builtin_bit_cast(f16x2, raw[j].y);
                f16x2 w2 = __builtin_bit_cast(f16x2, wls[wave][e + j][head]);
                a01[j & 3] += w2 * lo;
                a23[j & 3] += w2 * hi;
            }
        }
        for (; e + 4 <= deg; e += 4) {
#pragma unroll
            for (int j = 0; j < 4; j++) {
                int dd = dls[wave][e + j];
                uint2 raw = *(const uint2*)(H + (size_t)dd * 256 + lane * 4);
                f16x2 lo = __builtin_bit_cast(f16x2, raw.x);
                f16x2 hi = __builtin_bit_cast(f16x2, raw.y);
                f16x2 w2 = __builtin_bit_cast(f16x2, wls[wave][e + j][head]);
                a01[j] += w2 * lo;
                a23[j] += w2 * hi;
            }
        }
        for (; e < deg; e++) {
            int dd = dls[wave][e];
            uint2 raw = *(const uint2*)(H + (size_t)dd * 256 + lane * 4);
            f16x2 lo = __builtin_bit_cast(f16x2, raw.x);
            f16x2 hi = __builtin_bit_cast(f16x2, raw.y);
            f16x2 w2 = __builtin_bit_cast(f16x2, wls[wave][e][head]);
            a01[0] += w2 * lo;
            a23[0] += w2 * hi;
        }
        r0 = (float)a01[0][0] + (float)a01[1][0] + (float)a01[2][0] + (float)a01[3][0];
        r1 = (float)a01[0][1] + (float)a01[1][1] + (float)a01[2][1] + (float)a01[3][1];
        r2 = (float)a23[0][0] + (float)a23[1][0] + (float)a23[2][0] + (float)a23[3][0];
        r3 = (float)a23[0][1] + (float)a23[1][1] + (float)a23[2][1] + (float)a23[3][1];
    } else {
        float4 m = make_float4(-3e38f, -3e38f, -3e38f, -3e38f);
        for (int e = beg + lane; e < end; e += 64) {
            int d = edged[e];
            float4 sc = score4(s1v, *(const float4*)(s2 + (size_t)d * 4));
            m.x = fmaxf(m.x, sc.x); m.y = fmaxf(m.y, sc.y); m.z = fmaxf(m.z, sc.z); m.w = fmaxf(m.w, sc.w);
        }
#pragma unroll
        for (int off = 32; off > 0; off >>= 1) {
            m.x = fmaxf(m.x, __shfl_xor(m.x, off));
            m.y = fmaxf(m.y, __shfl_xor(m.y, off));
            m.z = fmaxf(m.z, __shfl_xor(m.z, off));
            m.w = fmaxf(m.w, __shfl_xor(m.w, off));
        }
        float4 sm = make_float4(0.f, 0.f, 0.f, 0.f);
        for (int e = beg + lane; e < end; e += 64) {
            int d = edged[e];
            float4 sc = score4(s1v, *(const float4*)(s2 + (size_t)d * 4));
            sm.x += __expf(sc.x - m.x); sm.y += __expf(sc.y - m.y);
            sm.z += __expf(sc.z - m.z); sm.w += __expf(sc.w - m.w);
        }
#pragma unroll
        for (int off = 32; off > 0; off >>= 1) {
            sm.x += __shfl_xor(sm.x, off);
            sm.y += __shfl_xor(sm.y, off);
            sm.z += __shfl_xor(sm.z, off);
            sm.w += __shfl_xor(sm.w, off);
        }
        float4 inv = make_float4(1.f / sm.x, 1.f / sm.y, 1.f / sm.z, 1.f / sm.w);
        float4 acc = make_float4(0.f, 0.f, 0.f, 0.f);
        for (int e = beg; e < end; e++) {
            int dd = edged[e];
            float4 sc = score4(s1v, *(const float4*)(s2 + (size_t)dd * 4));
            float wv[4] = { __expf(sc.x - m.x) * inv.x, __expf(sc.y - m.y) * inv.y,
                            __expf(sc.z - m.z) * inv.z, __expf(sc.w - m.w) * inv.w };
            float w = (head == 0) ? wv[0] : (head == 1) ? wv[1] : (head == 2) ? wv[2] : wv[3];
            const f16* hp = H + (size_t)dd * 256 + lane * 4;
            acc.x += w * (float)hp[0]; acc.y += w * (float)hp[1];
            acc.z += w * (float)hp[2]; acc.w += w * (float)hp[3];
        }
        r0 = acc.x; r1 = acc.y; r2 = acc.z; r3 = acc.w;
    }
    r0 = (r0 > 0.f) ? r0 : (__expf(r0) - 1.f);
    r1 = (r1 > 0.f) ? r1 : (__expf(r1) - 1.f);
    r2 = (r2 > 0.f) ? r2 : (__expf(r2) - 1.f);
    r3 = (r3 > 0.f) ? r3 : (__expf(r3) - 1.f);
    f16x2 o0 = (f16x2){(f16)r0, (f16)r1};
    f16x2 o1 = (f16x2){(f16)r2, (f16)r3};
    *(uint2*)outp = make_uint2(__builtin_bit_cast(unsigned, o0), __builtin_bit_cast(unsigned, o1));
}

// ---------------- layer-2 aggregate ----------------
__global__ __launch_bounds__(256) void agg_l2(const int* __restrict__ rowst, const int* __restrict__ cnt,
                                              const int* __restrict__ edged,
                                              const float* __restrict__ s1, const float* __restrict__ s2,
                                              const f16* __restrict__ H, float* __restrict__ outp, int N) {
    __shared__ float wls[4][64];
    __shared__ int dls[4][64];
    const int t = threadIdx.x, lane = t & 63, wave = t >> 6;
    const int node = blockIdx.x * 4 + wave;
    if (node >= N) return;
    const int beg = rowst[node];
    const int deg = cnt[node];
    const int end = beg + deg;
    if (deg == 0) { outp[(size_t)node * 64 + lane] = 0.f; return; }
    const float s1v = s1[node];

    float acc = 0.f;
    if (deg <= 64) {
        int d = 0;
        if (lane < deg) d = edged[beg + lane];
        dls[wave][lane] = d;
        float z = s1v + s2[d];
        float sc = (lane < deg) ? nlrelu(z) : -3e38f;
        float m = sc;
#pragma unroll
        for (int off = 32; off > 0; off >>= 1) m = fmaxf(m, __shfl_xor(m, off));
        float ex = (lane < deg) ? __expf(sc - m) : 0.f;
        float sm = ex;
#pragma unroll
        for (int off = 32; off > 0; off >>= 1) sm += __shfl_xor(sm, off);
        wls[wave][lane] = ex / sm;
        int e = 0;
        for (; e + 4 <= deg; e += 4) {
            int d0 = dls[wave][e], d1 = dls[wave][e + 1], d2 = dls[wave][e + 2], d3 = dls[wave][e + 3];
            float h0 = (float)H[(size_t)d0 * 64 + lane];
            float h1 = (float)H[(size_t)d1 * 64 + lane];
            float h2 = (float)H[(size_t)d2 * 64 + lane];
            float h3 = (float)H[(size_t)d3 * 64 + lane];
            acc += wls[wave][e] * h0 + wls[wave][e + 1] * h1 + wls[wave][e + 2] * h2 + wls[wave][e + 3] * h3;
        }
        for (; e < deg; e++)
            acc += wls[wave][e] * (float)H[(size_t)dls[wave][e] * 64 + lane];
    } else {
        float m = -3e38f;
        for (int e = beg + lane; e < end; e += 64) {
            int d = edged[e];
            m = fmaxf(m, nlrelu(s1v + s2[d]));
        }
#pragma unroll
        for (int off = 32; off > 0; off >>= 1) m = fmaxf(m, __shfl_xor(m, off));
        float sm = 0.f;
        for (int e = beg + lane; e < end; e += 64) {
            int d = edged[e];
            sm += __expf(nlrelu(s1v + s2[d]) - m);
        }
#pragma unroll
        for (int off = 32; off > 0; off >>= 1) sm += __shfl_xor(sm, off);
        float inv = 1.f / sm;
        for (int e = beg; e < end; e++) {
            int dd = edged[e];
            float w = __expf(nlrelu(s1v + s2[dd]) - m) * inv;
            acc += w * (float)H[(size_t)dd * 64 + lane];
        }
    }
    outp[(size_t)node * 64 + lane] = acc;
}

extern "C" void kernel_launch(void* const* d_in, const int* in_sizes, int n_in,
                              void* d_out, int out_size, void* d_ws, size_t ws_size,
                              hipStream_t stream) {
    const float* x     = (const float*)d_in[0];
    const int*   ei    = (const int*)d_in[1];     // [2][E] int32
    const float* Wh    = (const float*)d_in[2];
    const float* attnH = (const float*)d_in[3];
    const float* Wo    = (const float*)d_in[4];
    const float* attnO = (const float*)d_in[5];
    float* out         = (float*)d_out;

    const int N = in_sizes[0] / 128;    // 50000
    const int E = in_sizes[1] / 2;      // 800000
    const int* srcp = ei;
    const int* dstp = ei + E;

    char* base = (char*)d_ws;
    size_t off = 0;
    auto take = [&](size_t b) { void* p = base + off; off += (b + 255) & ~(size_t)255; return p; };
    f16*   B1     = (f16*)  take(32768 * 2);
    f16*   B2     = (f16*)  take(16384 * 2);
    int*   counts = (int*)  take((size_t)N * 4);
    int*   rowst  = (int*)  take((size_t)N * 4);
    int*   pos    = (int*)  take((size_t)E * 4);
    int*   edged  = (int*)  take((size_t)E * 4);
    int*   cursor = (int*)  take(256);
    float* s1     = (float*)take((size_t)N * 4 * 4);
    float* s2     = (float*)take((size_t)N * 4 * 4);
    float* s1b    = (float*)take((size_t)N * 4);
    float* s2b    = (float*)take((size_t)N * 4);
    f16*   H1     = (f16*)  take((size_t)N * 256 * 2);
    f16*   hcat   = (f16*)  take((size_t)N * 256 * 2);
    f16*   H2     = (f16*)  take((size_t)N * 64 * 2);

    hipMemsetAsync(counts, 0, (size_t)N * 4, stream);
    hipMemsetAsync(cursor, 0, 4, stream);

    const int eb4 = (E + 1023) / 1024;
    k_initcnt<<<192 + eb4, 256, 0, stream>>>(Wh, Wo, B1, B2, srcp, counts, pos, E, N);

    const int nb = (N + 1023) / 1024;
    scan_ticket<<<nb, 1024, 0, stream>>>(counts, rowst, cursor, N);

    scatter_noat<<<eb4, 256, 0, stream>>>(srcp, dstp, rowst, pos, edged, E, N);

    const int Gg = (N + 63) / 64;
    gemm1_f16<<<Gg, 256, 0, stream>>>(x, B1, attnH, H1, s1, s2, N);
    agg_l1<<<(N + 3) / 4, 256, 0, stream>>>(rowst, counts, edged, s1, s2, H1, hcat, N);
    gemm2_f16<<<Gg, 256, 0, stream>>>(hcat, B2, attnO, H2, s1b, s2b, N);
    agg_l2<<<(N + 3) / 4, 256, 0, stream>>>(rowst, counts, edged, s1b, s2b, H2, out, N);
}